// Round 6
// baseline (1524.193 us; speedup 1.0000x reference)
//
#include <hip/hip_runtime.h>

typedef unsigned short u16;
typedef unsigned int   u32;
typedef short v8s __attribute__((ext_vector_type(8)));
typedef float v4f __attribute__((ext_vector_type(4)));
typedef u16   v4u __attribute__((ext_vector_type(4)));

__device__ __forceinline__ float bf2f(u16 u) {
    union { float f; u32 i; } c; c.i = ((u32)u) << 16; return c.f;
}
__device__ __forceinline__ u16 f2bf(float f) {
    union { float f; u32 i; } c; c.f = f;
    u32 x = c.i;
    return (u16)((x + 0x7fffu + ((x >> 16) & 1u)) >> 16);
}
__device__ __forceinline__ float ldw(const void* p, long i, int flag) {
    return flag ? bf2f(((const u16*)p)[i]) : ((const float*)p)[i];
}

// ---------------------------------------------------------------------------
// dtype detector (round-3 validated: flag=0 on this harness -> fp32 inputs)
// ---------------------------------------------------------------------------
__global__ void detect_k(const u32* __restrict__ w, u32* __restrict__ meta) {
    __shared__ int cnt;
    if (threadIdx.x == 0) cnt = 0;
    __syncthreads();
    u32 v = w[(size_t)threadIdx.x * 4099];
    u32 f = (v >> 7) & 0xFFu;
    if (f >= 0x60u && f < 0x7Fu) atomicAdd(&cnt, 1);
    __syncthreads();
    if (threadIdx.x == 0) meta[0] = (cnt >= 192) ? 1u : 0u;
}

// Convert input (bf16 or fp32 per flag) -> bf16 hi/lo pair, 4 elems/thread.
__global__ void cvt_pair(const void* __restrict__ in, u16* __restrict__ hi,
                         u16* __restrict__ lo, const u32* __restrict__ meta, int n) {
    const int flag = meta[0];
    const int n4 = n >> 2;
    const int stride = gridDim.x * blockDim.x;
    for (int i = blockIdx.x * blockDim.x + threadIdx.x; i < n4; i += stride) {
        v4u h, l;
        if (flag) {
            h = *(const v4u*)((const u16*)in + (size_t)i * 4);
            l[0] = l[1] = l[2] = l[3] = 0;
        } else {
            v4f v = *(const v4f*)((const float*)in + (size_t)i * 4);
            #pragma unroll
            for (int r = 0; r < 4; ++r) {
                h[r] = f2bf(v[r]);
                l[r] = f2bf(v[r] - bf2f(h[r]));
            }
        }
        *(v4u*)(hi + (size_t)i * 4) = h;
        *(v4u*)(lo + (size_t)i * 4) = l;
    }
}

// One-time W2 transpose: W2[f*25+kc][fo] -> W2t{h,l}[fo][kc*32+f] (bf16 pair)
__global__ void w2t_k(const void* __restrict__ W2, const u32* __restrict__ meta,
                      u16* __restrict__ W2th, u16* __restrict__ W2tl) {
    const int flag = meta[0];
    const int i = blockIdx.x * 256 + threadIdx.x;
    if (i >= 51200) return;
    const int k = i >> 6, fo = i & 63;
    const float w = ldw(W2, (size_t)k * 64 + fo, flag);
    const int f = k / 25, kc = k % 25;
    const u16 h = f2bf(w);
    W2th[(size_t)fo * 800 + kc * 32 + f] = h;
    W2tl[(size_t)fo * 800 + kc * 32 + f] = f2bf(w - bf2f(h));
}

__global__ void zero_k(float* __restrict__ p, int n) {
    int i = blockIdx.x * blockDim.x + threadIdx.x;
    if (i < n) p[i] = 0.f;
}

// ---------------------------------------------------------------------------
// Tiled Cheb GEMM: C = alpha*(Lhi+Llo)@(Bhi+Blo) - (Ahi+Alo)   (3 products)
// Block: 64(M) x 64(N) tile, 4 waves (2x2), each wave 32x32 via 2x2 MFMA
// 16x16x32 tiles. LDS: 4 components [64 rows][64+8 pad halfwords] = 36 KB.
// FUSED=1: recurrence epilogue + hi/lo split + transposed Xt write (layer 2).
// FUSED=0: fp32 split-K partials to Cpart[chunk] (layer 1).
// ---------------------------------------------------------------------------
template<int FUSED>
__global__ __launch_bounds__(256) void cheb_tile(
    const u16* __restrict__ Lhi, const u16* __restrict__ Llo,
    const u16* __restrict__ Bhi, const u16* __restrict__ Blo,
    const u16* __restrict__ Ahi, const u16* __restrict__ Alo,
    u16* __restrict__ Chi, u16* __restrict__ Clo, float* __restrict__ Cpart,
    u16* __restrict__ Xt,
    int M, int V, int NC, int kc, float alpha, int useA)
{
    __shared__ u16 smem[4 * 64 * 72];            // Ah | Al | Bh | Bl, rows padded to 72
    const int tid  = threadIdx.x;
    const int wave = tid >> 6;
    const int lane = tid & 63;
    const int r16  = lane & 15;
    const int quad = lane >> 4;
    const int wm = wave & 1, wn = wave >> 1;

    const int m0 = blockIdx.x * 64;
    const int n0 = blockIdx.y * 64;
    const int k0 = blockIdx.z * kc;

    const int sr = lane >> 3;
    const int sc = lane & 7;
    const int rloc = wave * 16 + sr;
    const int lw  = rloc * 72 + sc * 8;

    v4f acc[2][2];
    #pragma unroll
    for (int i = 0; i < 2; ++i)
        #pragma unroll
        for (int j = 0; j < 2; ++j) acc[i][j] = (v4f){0.f, 0.f, 0.f, 0.f};

    const int arow0 = (wm * 32 + r16) * 72;
    const int arow1 = arow0 + 16 * 72;
    const int brow0 = (wn * 32 + r16) * 72 + 9216;
    const int brow1 = brow0 + 16 * 72;

    const int stages = kc >> 6;
    for (int st = 0; st < stages; ++st) {
        const int kk = k0 + st * 64;
        const size_t gA = (size_t)(m0 + rloc) * V + kk + sc * 8;
        const size_t gB = (size_t)(n0 + rloc) * V + kk + sc * 8;
        const size_t j8 = (size_t)8 * V;

        v8s t0 = *(const v8s*)(Lhi + gA);
        v8s t1 = *(const v8s*)(Lhi + gA + j8);
        v8s t2 = *(const v8s*)(Llo + gA);
        v8s t3 = *(const v8s*)(Llo + gA + j8);
        v8s t4 = *(const v8s*)(Bhi + gB);
        v8s t5 = *(const v8s*)(Bhi + gB + j8);
        v8s t6 = *(const v8s*)(Blo + gB);
        v8s t7 = *(const v8s*)(Blo + gB + j8);

        __syncthreads();
        *(v8s*)(smem +         lw)       = t0;
        *(v8s*)(smem +         lw + 576) = t1;
        *(v8s*)(smem +  4608 + lw)       = t2;
        *(v8s*)(smem +  4608 + lw + 576) = t3;
        *(v8s*)(smem +  9216 + lw)       = t4;
        *(v8s*)(smem +  9216 + lw + 576) = t5;
        *(v8s*)(smem + 13824 + lw)       = t6;
        *(v8s*)(smem + 13824 + lw + 576) = t7;
        __syncthreads();

        #pragma unroll
        for (int s = 0; s < 2; ++s) {
            const int qo = (s * 4 + quad) * 8;
            v8s ah0 = *(const v8s*)(smem + arow0 + qo);
            v8s ah1 = *(const v8s*)(smem + arow1 + qo);
            v8s al0 = *(const v8s*)(smem + 4608 + arow0 + qo);
            v8s al1 = *(const v8s*)(smem + 4608 + arow1 + qo);
            v8s bh0 = *(const v8s*)(smem + brow0 + qo);
            v8s bh1 = *(const v8s*)(smem + brow1 + qo);
            v8s bl0 = *(const v8s*)(smem + 4608 + brow0 + qo);
            v8s bl1 = *(const v8s*)(smem + 4608 + brow1 + qo);

            acc[0][0] = __builtin_amdgcn_mfma_f32_16x16x32_bf16(ah0, bh0, acc[0][0], 0, 0, 0);
            acc[0][0] = __builtin_amdgcn_mfma_f32_16x16x32_bf16(ah0, bl0, acc[0][0], 0, 0, 0);
            acc[0][0] = __builtin_amdgcn_mfma_f32_16x16x32_bf16(al0, bh0, acc[0][0], 0, 0, 0);
            acc[0][1] = __builtin_amdgcn_mfma_f32_16x16x32_bf16(ah0, bh1, acc[0][1], 0, 0, 0);
            acc[0][1] = __builtin_amdgcn_mfma_f32_16x16x32_bf16(ah0, bl1, acc[0][1], 0, 0, 0);
            acc[0][1] = __builtin_amdgcn_mfma_f32_16x16x32_bf16(al0, bh1, acc[0][1], 0, 0, 0);
            acc[1][0] = __builtin_amdgcn_mfma_f32_16x16x32_bf16(ah1, bh0, acc[1][0], 0, 0, 0);
            acc[1][0] = __builtin_amdgcn_mfma_f32_16x16x32_bf16(ah1, bl0, acc[1][0], 0, 0, 0);
            acc[1][0] = __builtin_amdgcn_mfma_f32_16x16x32_bf16(al1, bh0, acc[1][0], 0, 0, 0);
            acc[1][1] = __builtin_amdgcn_mfma_f32_16x16x32_bf16(ah1, bh1, acc[1][1], 0, 0, 0);
            acc[1][1] = __builtin_amdgcn_mfma_f32_16x16x32_bf16(ah1, bl1, acc[1][1], 0, 0, 0);
            acc[1][1] = __builtin_amdgcn_mfma_f32_16x16x32_bf16(al1, bh1, acc[1][1], 0, 0, 0);
        }
    }

    #pragma unroll
    for (int j = 0; j < 2; ++j) {
        const int n = n0 + wn * 32 + j * 16 + r16;
        #pragma unroll
        for (int i = 0; i < 2; ++i) {
            const int mrow = m0 + wm * 32 + i * 16 + quad * 4;
            if (FUSED) {
                const size_t obase = (size_t)n * M + mrow;
                float vals[4];
                if (useA) {
                    v4u ah4 = *(const v4u*)(Ahi + obase);
                    v4u al4 = *(const v4u*)(Alo + obase);
                    #pragma unroll
                    for (int r = 0; r < 4; ++r)
                        vals[r] = alpha * acc[i][j][r] - (bf2f(ah4[r]) + bf2f(al4[r]));
                } else {
                    #pragma unroll
                    for (int r = 0; r < 4; ++r) vals[r] = alpha * acc[i][j][r];
                }
                v4u hi, lo;
                #pragma unroll
                for (int r = 0; r < 4; ++r) {
                    u16 h = f2bf(vals[r]);
                    hi[r] = h;
                    lo[r] = f2bf(vals[r] - bf2f(h));
                }
                *(v4u*)(Chi + obase) = hi;
                *(v4u*)(Clo + obase) = lo;
                // transposed copy for lin2 MFMA: Xt[(nb*1024 + u)*32 + f]
                const int nb = n >> 5, f = n & 31;
                u16* xt = Xt + ((size_t)(nb * 1024) + mrow) * 32 + f;
                #pragma unroll
                for (int r = 0; r < 4; ++r) xt[r * 32] = hi[r];
            } else {
                float* cp = Cpart + ((size_t)(blockIdx.z * NC + n)) * M + mrow;
                *(v4f*)cp = acc[i][j];
            }
        }
    }
}

// Combine split-K partials + recurrence epilogue + hi/lo split (layer 1).
__global__ __launch_bounds__(256) void cheb_comb(
    const float* __restrict__ Cpart, const u16* __restrict__ Ahi, const u16* __restrict__ Alo,
    u16* __restrict__ Chi, u16* __restrict__ Clo, int total, int nkc, float alpha, int useA)
{
    const int idx = blockIdx.x * 256 + threadIdx.x;
    if (idx >= total) return;
    float s = 0.f;
    for (int c = 0; c < nkc; ++c) s += Cpart[(size_t)c * total + idx];
    float v = alpha * s;
    if (useA) v -= bf2f(Ahi[idx]) + bf2f(Alo[idx]);
    u16 h = f2bf(v);
    Chi[idx] = h;
    Clo[idx] = f2bf(v - bf2f(h));
}

// ---------------------------------------------------------------------------
// Linear1 (25->32) + bias + relu + maxpool4 -> layer-2 slice0 (hi/lo) + Xt0
// ---------------------------------------------------------------------------
__global__ __launch_bounds__(256) void lin1_pool(
    const u16* __restrict__ Shi, const void* __restrict__ W1, const void* __restrict__ b1,
    const u32* __restrict__ meta, u16* __restrict__ Ohi, u16* __restrict__ Olo,
    u16* __restrict__ Xt0)
{
    const int flag = meta[0];
    const int m1 = blockIdx.x * 64 + threadIdx.x;   // 0..1023
    const int f  = blockIdx.y * 4 + threadIdx.y;    // 0..31
    const int n  = blockIdx.z;                      // 0..63
    float a0 = 0.f, a1 = 0.f, a2 = 0.f, a3 = 0.f;
    const size_t base = (size_t)n * 4096 + (size_t)m1 * 4;
    #pragma unroll
    for (int k = 0; k < 25; ++k) {
        v4u h4 = *(const v4u*)(Shi + (size_t)k * 262144 + base);
        float w = ldw(W1, k * 32 + f, flag);
        a0 += bf2f(h4[0]) * w;
        a1 += bf2f(h4[1]) * w;
        a2 += bf2f(h4[2]) * w;
        a3 += bf2f(h4[3]) * w;
    }
    const float b = ldw(b1, f, flag);
    float v = fmaxf(fmaxf(a0, a1), fmaxf(a2, a3)) + b;
    v = fmaxf(v, 0.f);
    const size_t oi = ((size_t)n * 32 + f) * 1024 + m1;
    u16 h = f2bf(v);
    Ohi[oi] = h;
    Olo[oi] = f2bf(v - bf2f(h));
    Xt0[((size_t)n * 1024 + m1) * 32 + f] = h;
}

// ---------------------------------------------------------------------------
// MFMA linear-2 accumulation over a group of up to 3 slices.
// ---------------------------------------------------------------------------
__global__ __launch_bounds__(256) void lin2_mfma(
    const u16* __restrict__ Xt0, const u16* __restrict__ Xt1, const u16* __restrict__ Xt2,
    const u16* __restrict__ W2th, const u16* __restrict__ W2tl,
    float* __restrict__ acc, int k0, int cnt, int zi)
{
    const int tid  = threadIdx.x;
    const int wave = tid >> 6;
    const int lane = tid & 63;
    const int r16  = lane & 15;
    const int quad = lane >> 4;
    const int n  = blockIdx.y;
    const int u0 = blockIdx.x * 128 + wave * 32;

    v4f a[2][4];
    #pragma unroll
    for (int i = 0; i < 2; ++i)
        #pragma unroll
        for (int j = 0; j < 4; ++j) a[i][j] = (v4f){0.f, 0.f, 0.f, 0.f};

    const u16* Xs[3] = {Xt0, Xt1, Xt2};
    for (int c = 0; c < cnt; ++c) {
        const u16* X = Xs[c];
        v8s a0 = *(const v8s*)(X + ((size_t)n * 1024 + u0 + r16) * 32 + quad * 8);
        v8s a1 = *(const v8s*)(X + ((size_t)n * 1024 + u0 + 16 + r16) * 32 + quad * 8);
        const int kb = (k0 + c) * 32 + quad * 8;
        #pragma unroll
        for (int j = 0; j < 4; ++j) {
            const size_t wrow = (size_t)(j * 16 + r16) * 800 + kb;
            v8s bh = *(const v8s*)(W2th + wrow);
            v8s bl = *(const v8s*)(W2tl + wrow);
            a[0][j] = __builtin_amdgcn_mfma_f32_16x16x32_bf16(a0, bh, a[0][j], 0, 0, 0);
            a[0][j] = __builtin_amdgcn_mfma_f32_16x16x32_bf16(a0, bl, a[0][j], 0, 0, 0);
            a[1][j] = __builtin_amdgcn_mfma_f32_16x16x32_bf16(a1, bh, a[1][j], 0, 0, 0);
            a[1][j] = __builtin_amdgcn_mfma_f32_16x16x32_bf16(a1, bl, a[1][j], 0, 0, 0);
        }
    }

    #pragma unroll
    for (int i = 0; i < 2; ++i) {
        const int u = u0 + i * 16 + quad * 4;
        #pragma unroll
        for (int j = 0; j < 4; ++j) {
            const int fo = j * 16 + r16;
            float* p = acc + ((size_t)n * 1024 + u) * 64 + fo;
            if (zi) {
                #pragma unroll
                for (int r = 0; r < 4; ++r) p[r * 64] = a[i][j][r];
            } else {
                #pragma unroll
                for (int r = 0; r < 4; ++r) p[r * 64] += a[i][j][r];
            }
        }
    }
}

// Finish linear-2: bias + relu + maxpool4 -> hbuf fp32 [n][m2*64+fo]
__global__ __launch_bounds__(256) void lin2fin(
    const float* __restrict__ acc, const void* __restrict__ b2, const u32* __restrict__ meta,
    float* __restrict__ hbuf)
{
    const int flag = meta[0];
    const int fo = threadIdx.x;
    const int m2 = blockIdx.x * 4 + threadIdx.y;
    const int n  = blockIdx.y;
    const size_t b = ((size_t)n * 1024 + (size_t)m2 * 4) * 64 + fo;
    float v = fmaxf(fmaxf(acc[b], acc[b + 64]), fmaxf(acc[b + 128], acc[b + 192]));
    v = fmaxf(v + ldw(b2, fo, flag), 0.f);
    hbuf[(size_t)n * 16384 + (size_t)m2 * 64 + fo] = v;
}

// FC1: (64,16384) @ (16384,512), split-i atomics into fp32 partials.
// Grid (128,8): i-chunk=128 -> 1024 blocks (4 waves/SIMD, was 1 at grid 32x8).
__global__ __launch_bounds__(256) void fc1_k(
    const float* __restrict__ hbuf, const void* __restrict__ Wh,
    const u32* __restrict__ meta, float* __restrict__ part)
{
    const int flag = meta[0];
    const int h0 = threadIdx.x * 2;
    const int ic = blockIdx.x;         // 0..127
    const int nb = blockIdx.y;         // 0..7
    float a[8][2];
    #pragma unroll
    for (int nn = 0; nn < 8; ++nn) { a[nn][0] = 0.f; a[nn][1] = 0.f; }
    const int i0 = ic * 128;
    if (flag) {
        const u16* whp = (const u16*)Wh;
        for (int i = i0; i < i0 + 128; ++i) {
            const u32 wp = *(const u32*)(whp + (size_t)i * 512 + h0);
            const float w0 = bf2f((u16)(wp & 0xffffu));
            const float w1 = bf2f((u16)(wp >> 16));
            #pragma unroll
            for (int nn = 0; nn < 8; ++nn) {
                const float hv = hbuf[(size_t)(nb * 8 + nn) * 16384 + i];
                a[nn][0] += hv * w0;
                a[nn][1] += hv * w1;
            }
        }
    } else {
        const float* whp = (const float*)Wh;
        for (int i = i0; i < i0 + 128; ++i) {
            const float w0 = whp[(size_t)i * 512 + h0];
            const float w1 = whp[(size_t)i * 512 + h0 + 1];
            #pragma unroll
            for (int nn = 0; nn < 8; ++nn) {
                const float hv = hbuf[(size_t)(nb * 8 + nn) * 16384 + i];
                a[nn][0] += hv * w0;
                a[nn][1] += hv * w1;
            }
        }
    }
    #pragma unroll
    for (int nn = 0; nn < 8; ++nn) {
        atomicAdd(&part[(size_t)(nb * 8 + nn) * 512 + h0],     a[nn][0]);
        atomicAdd(&part[(size_t)(nb * 8 + nn) * 512 + h0 + 1], a[nn][1]);
    }
}

// FC1 bias+relu fused with FC2
__global__ void fc2_k(
    const float* __restrict__ part, const void* __restrict__ bh,
    const void* __restrict__ Wo, const void* __restrict__ bo,
    const u32* __restrict__ meta, void* __restrict__ out)
{
    const int flag = meta[0];
    const int n = blockIdx.x;
    const int lane = threadIdx.x;   // 64 = 1 wave
    float p[10];
    #pragma unroll
    for (int o = 0; o < 10; ++o) p[o] = 0.f;
    for (int j = lane; j < 512; j += 64) {
        const float r = fmaxf(part[(size_t)n * 512 + j] + ldw(bh, j, flag), 0.f);
        #pragma unroll
        for (int o = 0; o < 10; ++o) p[o] += r * ldw(Wo, j * 10 + o, flag);
    }
    #pragma unroll
    for (int o = 0; o < 10; ++o) {
        for (int off = 32; off > 0; off >>= 1) p[o] += __shfl_down(p[o], off);
    }
    if (lane == 0) {
        #pragma unroll
        for (int o = 0; o < 10; ++o) {
            float v = p[o] + ldw(bo, o, flag);
            if (flag) ((u16*)out)[n * 10 + o] = f2bf(v);
            else      ((float*)out)[n * 10 + o] = v;
        }
    }
}

extern "C" void kernel_launch(void* const* d_in, const int* in_sizes, int n_in,
                              void* d_out, int out_size, void* d_ws, size_t ws_size,
                              hipStream_t stream)
{
    const void* x  = d_in[0];
    const void* L0 = d_in[1];
    const void* L1 = d_in[2];
    const void* W1 = d_in[3];
    const void* b1 = d_in[4];
    const void* W2 = d_in[5];
    const void* b2 = d_in[6];
    const void* Wh = d_in[7];
    const void* bh = d_in[8];
    const void* Wo = d_in[9];
    const void* bo = d_in[10];

    // ---- workspace carve-up (~135.1 MB; rounds 3-5 proved ws >= 135.1 MB) ----
    char* base = (char*)d_ws;
    size_t off = 0;
    u32*  meta = (u32*)(base + off);      off += 256;
    u16*  L0hi = (u16*)(base + off);      off += (size_t)33554432;
    u16*  L0lo = (u16*)(base + off);      off += (size_t)33554432;
    u16*  L1hi = (u16*)(base + off);      off += (size_t)2097152;
    u16*  L1lo = (u16*)(base + off);      off += (size_t)2097152;
    u16*  A1hi = (u16*)(base + off);      off += (size_t)25 * 524288;   // dead after lin1 -> Xt slots 1,2
    u16*  A1lo = (u16*)(base + off);      off += (size_t)3 * 524288;    // dead after layer-1 -> Xt slot 0 (+extra)
    off += (size_t)4194304 - 3 * 524288;  // Xt slot 0 needs 4 MiB total
    u16*  A2hi = (u16*)(base + off);      off += (size_t)3 * 4194304;
    u16*  A2lo = (u16*)(base + off);      off += (size_t)3 * 4194304;
    float* ACC2 = (float*)(base + off);   off += (size_t)16777216;
    float* hbuf = (float*)(base + off);   off += (size_t)4194304;
    float* part = (float*)(base + off);   off += (size_t)131072;
    u16*  W2th = (u16*)(base + off);      off += (size_t)102400;
    u16*  W2tl = (u16*)(base + off);      off += (size_t)102400;
    float* cpart = ACC2;            // overlay: cpart (16 x 1 MB = 16.78 MB) == ACC2 exactly
    u16* Xt[3] = { A1lo, A1hi, A1hi + 2097152 };

    // dtype detection + canonical hi/lo conversion + W2 transpose
    detect_k<<<1, 256, 0, stream>>>((const u32*)L0, meta);
    cvt_pair<<<2048, 256, 0, stream>>>(L0, L0hi, L0lo, meta, 16777216);
    cvt_pair<<<256, 256, 0, stream>>>(L1, L1hi, L1lo, meta, 1048576);
    cvt_pair<<<64, 256, 0, stream>>>(x, A1hi, A1lo, meta, 262144);  // slice 0
    w2t_k<<<200, 256, 0, stream>>>(W2, meta, W2th, W2tl);

    // ---- layer-1 Chebyshev recurrence: tiled split-K x16 + combine ----
    for (int k = 1; k < 25; ++k) {
        cheb_tile<0><<<dim3(64, 1, 16), 256, 0, stream>>>(
            L0hi, L0lo,
            A1hi + (size_t)(k - 1) * 262144, A1lo + (size_t)((k - 1) % 3) * 262144,
            (const u16*)0, (const u16*)0, (u16*)0, (u16*)0, cpart, (u16*)0,
            4096, 4096, 64, 256, 0.f, 0);
        const u16* pAh = (k >= 2) ? A1hi + (size_t)(k - 2) * 262144 : A1hi;
        const u16* pAl = A1lo + (size_t)(((k >= 2) ? (k - 2) : 0) % 3) * 262144;
        cheb_comb<<<1024, 256, 0, stream>>>(
            cpart, pAh, pAl,
            A1hi + (size_t)k * 262144, A1lo + (size_t)(k % 3) * 262144,
            262144, 16, (k == 1) ? 1.f : 2.f, (k >= 2) ? 1 : 0);
    }

    // linear1 + relu + pool4 -> layer-2 slice 0 (hi/lo) + transposed Xt0
    lin1_pool<<<dim3(16, 8, 64), dim3(64, 4), 0, stream>>>(
        A1hi, W1, b1, meta, A2hi, A2lo, Xt[0]);

    // ---- layer-2 recurrence (tiled, fused epilogue + Xt) + grouped MFMA lin2
    for (int k = 1; k < 25; ++k) {
        const u16* pBh = A2hi + (size_t)((k - 1) % 3) * 2097152;
        const u16* pBl = A2lo + (size_t)((k - 1) % 3) * 2097152;
        const u16* pAh = A2hi + (size_t)(((k >= 2) ? (k - 2) : 0) % 3) * 2097152;
        const u16* pAl = A2lo + (size_t)(((k >= 2) ? (k - 2) : 0) % 3) * 2097152;
        u16* pCh = A2hi + (size_t)(k % 3) * 2097152;
        u16* pCl = A2lo + (size_t)(k % 3) * 2097152;
        cheb_tile<1><<<dim3(16, 32, 1), 256, 0, stream>>>(
            L1hi, L1lo, pBh, pBl, pAh, pAl, pCh, pCl, (float*)0, Xt[k % 3],
            1024, 1024, 2048, 1024, (k == 1) ? 1.f : 2.f, (k >= 2) ? 1 : 0);
        if (k >= 2 && ((k - 2) % 3) == 0) {
            lin2_mfma<<<dim3(8, 64), 256, 0, stream>>>(
                Xt[0], Xt[1], Xt[2], W2th, W2tl, ACC2, k - 2, 3, (k == 2) ? 1 : 0);
        }
    }
    // final group: slice 24 (24 % 3 == 0 -> slot 0)
    lin2_mfma<<<dim3(8, 64), 256, 0, stream>>>(
        Xt[0], Xt[0], Xt[0], W2th, W2tl, ACC2, 24, 1, 0);

    // finish linear2: bias + relu + pool4 -> hbuf fp32
    lin2fin<<<dim3(64, 64), dim3(64, 4), 0, stream>>>(ACC2, b2, meta, hbuf);

    // FC head
    zero_k<<<128, 256, 0, stream>>>(part, 32768);
    fc1_k<<<dim3(128, 8), 256, 0, stream>>>(hbuf, Wh, meta, part);
    fc2_k<<<64, 64, 0, stream>>>(part, bh, Wo, bo, meta, d_out);
}

// Round 7
// 1484.745 us; speedup vs baseline: 1.0266x; 1.0266x over previous
//
#include <hip/hip_runtime.h>

typedef unsigned short u16;
typedef unsigned int   u32;
typedef short v8s __attribute__((ext_vector_type(8)));
typedef float v4f __attribute__((ext_vector_type(4)));
typedef u16   v4u __attribute__((ext_vector_type(4)));

__device__ __forceinline__ float bf2f(u16 u) {
    union { float f; u32 i; } c; c.i = ((u32)u) << 16; return c.f;
}
__device__ __forceinline__ u16 f2bf(float f) {
    union { float f; u32 i; } c; c.f = f;
    u32 x = c.i;
    return (u16)((x + 0x7fffu + ((x >> 16) & 1u)) >> 16);
}
__device__ __forceinline__ float ldw(const void* p, long i, int flag) {
    return flag ? bf2f(((const u16*)p)[i]) : ((const float*)p)[i];
}

// ---------------------------------------------------------------------------
// dtype detector (round-3 validated: flag=0 on this harness -> fp32 inputs)
// ---------------------------------------------------------------------------
__global__ void detect_k(const u32* __restrict__ w, u32* __restrict__ meta) {
    __shared__ int cnt;
    if (threadIdx.x == 0) cnt = 0;
    __syncthreads();
    u32 v = w[(size_t)threadIdx.x * 4099];
    u32 f = (v >> 7) & 0xFFu;
    if (f >= 0x60u && f < 0x7Fu) atomicAdd(&cnt, 1);
    __syncthreads();
    if (threadIdx.x == 0) meta[0] = (cnt >= 192) ? 1u : 0u;
}

// Convert input (bf16 or fp32 per flag) -> bf16 hi/lo pair, 4 elems/thread.
__global__ void cvt_pair(const void* __restrict__ in, u16* __restrict__ hi,
                         u16* __restrict__ lo, const u32* __restrict__ meta, int n) {
    const int flag = meta[0];
    const int n4 = n >> 2;
    const int stride = gridDim.x * blockDim.x;
    for (int i = blockIdx.x * blockDim.x + threadIdx.x; i < n4; i += stride) {
        v4u h, l;
        if (flag) {
            h = *(const v4u*)((const u16*)in + (size_t)i * 4);
            l[0] = l[1] = l[2] = l[3] = 0;
        } else {
            v4f v = *(const v4f*)((const float*)in + (size_t)i * 4);
            #pragma unroll
            for (int r = 0; r < 4; ++r) {
                h[r] = f2bf(v[r]);
                l[r] = f2bf(v[r] - bf2f(h[r]));
            }
        }
        *(v4u*)(hi + (size_t)i * 4) = h;
        *(v4u*)(lo + (size_t)i * 4) = l;
    }
}

// One-time W2 transpose: W2[f*25+kc][fo] -> W2t{h,l}[fo][kc*32+f] (bf16 pair)
__global__ void w2t_k(const void* __restrict__ W2, const u32* __restrict__ meta,
                      u16* __restrict__ W2th, u16* __restrict__ W2tl) {
    const int flag = meta[0];
    const int i = blockIdx.x * 256 + threadIdx.x;
    if (i >= 51200) return;
    const int k = i >> 6, fo = i & 63;
    const float w = ldw(W2, (size_t)k * 64 + fo, flag);
    const int f = k / 25, kc = k % 25;
    const u16 h = f2bf(w);
    W2th[(size_t)fo * 800 + kc * 32 + f] = h;
    W2tl[(size_t)fo * 800 + kc * 32 + f] = f2bf(w - bf2f(h));
}

// ---------------------------------------------------------------------------
// Tiled Cheb GEMM: C = alpha*(Lhi+Llo)@(Bhi+Blo) - (Ahi+Alo)   (3 products)
// Block: 64(M) x 64(N) tile, 512 thr = 8 waves, each wave 32x16 (2x1 MFMA
// tiles, 16x16x32). LDS: 4 comps [64][72] = 36 KB -> 2 blocks/CU, 16 waves/CU.
// FUSED=1: recurrence epilogue + hi/lo split + transposed Xt write (layer 2).
// FUSED=0: fp32 split-K partials to Cpart[chunk] (layer 1).
// ---------------------------------------------------------------------------
template<int FUSED>
__global__ __launch_bounds__(512) void cheb_tile(
    const u16* __restrict__ Lhi, const u16* __restrict__ Llo,
    const u16* __restrict__ Bhi, const u16* __restrict__ Blo,
    const u16* __restrict__ Ahi, const u16* __restrict__ Alo,
    u16* __restrict__ Chi, u16* __restrict__ Clo, float* __restrict__ Cpart,
    u16* __restrict__ Xt,
    int M, int V, int NC, int kc, float alpha, int useA)
{
    __shared__ u16 smem[4 * 64 * 72];            // Ah | Al | Bh | Bl, rows padded to 72
    const int tid  = threadIdx.x;
    const int wave = tid >> 6;
    const int lane = tid & 63;
    const int r16  = lane & 15;
    const int quad = lane >> 4;
    const int wm = wave & 1;        // m-half (32 rows)
    const int wn = wave >> 1;       // n-quarter (16 cols)

    const int m0 = blockIdx.x * 64;
    const int n0 = blockIdx.y * 64;
    const int k0 = blockIdx.z * kc;

    // staging: each thread stages one 16B chunk per component
    const int srow = tid >> 3;      // 0..63
    const int sc   = tid & 7;       // 0..7 (k-chunk of 8 halfwords)
    const int lw   = srow * 72 + sc * 8;

    v4f acc[2];
    acc[0] = (v4f){0.f, 0.f, 0.f, 0.f};
    acc[1] = (v4f){0.f, 0.f, 0.f, 0.f};

    const int arow0 = (wm * 32 + r16) * 72;
    const int arow1 = arow0 + 16 * 72;
    const int brow  = (wn * 16 + r16) * 72 + 9216;

    const int stages = kc >> 6;
    for (int st = 0; st < stages; ++st) {
        const int kk = k0 + st * 64;
        const size_t gA = (size_t)(m0 + srow) * V + kk + sc * 8;
        const size_t gB = (size_t)(n0 + srow) * V + kk + sc * 8;

        v8s t0 = *(const v8s*)(Lhi + gA);
        v8s t1 = *(const v8s*)(Llo + gA);
        v8s t2 = *(const v8s*)(Bhi + gB);
        v8s t3 = *(const v8s*)(Blo + gB);

        __syncthreads();                          // prev compute done before overwrite
        *(v8s*)(smem +         lw) = t0;
        *(v8s*)(smem +  4608 + lw) = t1;
        *(v8s*)(smem +  9216 + lw) = t2;
        *(v8s*)(smem + 13824 + lw) = t3;
        __syncthreads();

        #pragma unroll
        for (int s = 0; s < 2; ++s) {
            const int qo = (s * 4 + quad) * 8;
            v8s ah0 = *(const v8s*)(smem + arow0 + qo);
            v8s ah1 = *(const v8s*)(smem + arow1 + qo);
            v8s al0 = *(const v8s*)(smem + 4608 + arow0 + qo);
            v8s al1 = *(const v8s*)(smem + 4608 + arow1 + qo);
            v8s bh  = *(const v8s*)(smem + brow + qo);
            v8s bl  = *(const v8s*)(smem + 4608 + brow + qo);

            acc[0] = __builtin_amdgcn_mfma_f32_16x16x32_bf16(ah0, bh, acc[0], 0, 0, 0);
            acc[0] = __builtin_amdgcn_mfma_f32_16x16x32_bf16(ah0, bl, acc[0], 0, 0, 0);
            acc[0] = __builtin_amdgcn_mfma_f32_16x16x32_bf16(al0, bh, acc[0], 0, 0, 0);
            acc[1] = __builtin_amdgcn_mfma_f32_16x16x32_bf16(ah1, bh, acc[1], 0, 0, 0);
            acc[1] = __builtin_amdgcn_mfma_f32_16x16x32_bf16(ah1, bl, acc[1], 0, 0, 0);
            acc[1] = __builtin_amdgcn_mfma_f32_16x16x32_bf16(al1, bh, acc[1], 0, 0, 0);
        }
    }

    const int n = n0 + wn * 16 + r16;
    #pragma unroll
    for (int i = 0; i < 2; ++i) {
        const int mrow = m0 + wm * 32 + i * 16 + quad * 4;
        if (FUSED) {
            const size_t obase = (size_t)n * M + mrow;
            float vals[4];
            if (useA) {
                v4u ah4 = *(const v4u*)(Ahi + obase);
                v4u al4 = *(const v4u*)(Alo + obase);
                #pragma unroll
                for (int r = 0; r < 4; ++r)
                    vals[r] = alpha * acc[i][r] - (bf2f(ah4[r]) + bf2f(al4[r]));
            } else {
                #pragma unroll
                for (int r = 0; r < 4; ++r) vals[r] = alpha * acc[i][r];
            }
            v4u hi, lo;
            #pragma unroll
            for (int r = 0; r < 4; ++r) {
                u16 h = f2bf(vals[r]);
                hi[r] = h;
                lo[r] = f2bf(vals[r] - bf2f(h));
            }
            *(v4u*)(Chi + obase) = hi;
            *(v4u*)(Clo + obase) = lo;
            // transposed copy for lin2 MFMA: Xt[(nb*1024 + u)*32 + f]
            const int nb = n >> 5, f = n & 31;
            u16* xt = Xt + ((size_t)(nb * 1024) + mrow) * 32 + f;
            #pragma unroll
            for (int r = 0; r < 4; ++r) xt[r * 32] = hi[r];
        } else {
            float* cp = Cpart + ((size_t)(blockIdx.z * NC + n)) * M + mrow;
            *(v4f*)cp = acc[i];
        }
    }
}

// Combine split-K partials + recurrence epilogue + hi/lo split (layer 1).
__global__ __launch_bounds__(256) void cheb_comb(
    const float* __restrict__ Cpart, const u16* __restrict__ Ahi, const u16* __restrict__ Alo,
    u16* __restrict__ Chi, u16* __restrict__ Clo, int total, int nkc, float alpha, int useA)
{
    const int idx = blockIdx.x * 256 + threadIdx.x;
    if (idx >= total) return;
    float s = 0.f;
    for (int c = 0; c < nkc; ++c) s += Cpart[(size_t)c * total + idx];
    float v = alpha * s;
    if (useA) v -= bf2f(Ahi[idx]) + bf2f(Alo[idx]);
    u16 h = f2bf(v);
    Chi[idx] = h;
    Clo[idx] = f2bf(v - bf2f(h));
}

// ---------------------------------------------------------------------------
// Linear1 (25->32) + bias + relu + maxpool4 -> layer-2 slice0 (hi/lo) + Xt0
// ---------------------------------------------------------------------------
__global__ __launch_bounds__(256) void lin1_pool(
    const u16* __restrict__ Shi, const void* __restrict__ W1, const void* __restrict__ b1,
    const u32* __restrict__ meta, u16* __restrict__ Ohi, u16* __restrict__ Olo,
    u16* __restrict__ Xt0)
{
    const int flag = meta[0];
    const int m1 = blockIdx.x * 64 + threadIdx.x;   // 0..1023
    const int f  = blockIdx.y * 4 + threadIdx.y;    // 0..31
    const int n  = blockIdx.z;                      // 0..63
    float a0 = 0.f, a1 = 0.f, a2 = 0.f, a3 = 0.f;
    const size_t base = (size_t)n * 4096 + (size_t)m1 * 4;
    #pragma unroll
    for (int k = 0; k < 25; ++k) {
        v4u h4 = *(const v4u*)(Shi + (size_t)k * 262144 + base);
        float w = ldw(W1, k * 32 + f, flag);
        a0 += bf2f(h4[0]) * w;
        a1 += bf2f(h4[1]) * w;
        a2 += bf2f(h4[2]) * w;
        a3 += bf2f(h4[3]) * w;
    }
    const float b = ldw(b1, f, flag);
    float v = fmaxf(fmaxf(a0, a1), fmaxf(a2, a3)) + b;
    v = fmaxf(v, 0.f);
    const size_t oi = ((size_t)n * 32 + f) * 1024 + m1;
    u16 h = f2bf(v);
    Ohi[oi] = h;
    Olo[oi] = f2bf(v - bf2f(h));
    Xt0[((size_t)n * 1024 + m1) * 32 + f] = h;
}

// ---------------------------------------------------------------------------
// MFMA linear-2 accumulation over a group of up to 3 slices.
// ---------------------------------------------------------------------------
__global__ __launch_bounds__(256) void lin2_mfma(
    const u16* __restrict__ Xt0, const u16* __restrict__ Xt1, const u16* __restrict__ Xt2,
    const u16* __restrict__ W2th, const u16* __restrict__ W2tl,
    float* __restrict__ acc, int k0, int cnt, int zi)
{
    const int tid  = threadIdx.x;
    const int wave = tid >> 6;
    const int lane = tid & 63;
    const int r16  = lane & 15;
    const int quad = lane >> 4;
    const int n  = blockIdx.y;
    const int u0 = blockIdx.x * 128 + wave * 32;

    v4f a[2][4];
    #pragma unroll
    for (int i = 0; i < 2; ++i)
        #pragma unroll
        for (int j = 0; j < 4; ++j) a[i][j] = (v4f){0.f, 0.f, 0.f, 0.f};

    const u16* Xs[3] = {Xt0, Xt1, Xt2};
    for (int c = 0; c < cnt; ++c) {
        const u16* X = Xs[c];
        v8s a0 = *(const v8s*)(X + ((size_t)n * 1024 + u0 + r16) * 32 + quad * 8);
        v8s a1 = *(const v8s*)(X + ((size_t)n * 1024 + u0 + 16 + r16) * 32 + quad * 8);
        const int kb = (k0 + c) * 32 + quad * 8;
        #pragma unroll
        for (int j = 0; j < 4; ++j) {
            const size_t wrow = (size_t)(j * 16 + r16) * 800 + kb;
            v8s bh = *(const v8s*)(W2th + wrow);
            v8s bl = *(const v8s*)(W2tl + wrow);
            a[0][j] = __builtin_amdgcn_mfma_f32_16x16x32_bf16(a0, bh, a[0][j], 0, 0, 0);
            a[0][j] = __builtin_amdgcn_mfma_f32_16x16x32_bf16(a0, bl, a[0][j], 0, 0, 0);
            a[1][j] = __builtin_amdgcn_mfma_f32_16x16x32_bf16(a1, bh, a[1][j], 0, 0, 0);
            a[1][j] = __builtin_amdgcn_mfma_f32_16x16x32_bf16(a1, bl, a[1][j], 0, 0, 0);
        }
    }

    #pragma unroll
    for (int i = 0; i < 2; ++i) {
        const int u = u0 + i * 16 + quad * 4;
        #pragma unroll
        for (int j = 0; j < 4; ++j) {
            const int fo = j * 16 + r16;
            float* p = acc + ((size_t)n * 1024 + u) * 64 + fo;
            if (zi) {
                #pragma unroll
                for (int r = 0; r < 4; ++r) p[r * 64] = a[i][j][r];
            } else {
                #pragma unroll
                for (int r = 0; r < 4; ++r) p[r * 64] += a[i][j][r];
            }
        }
    }
}

// Finish linear-2: bias + relu + maxpool4 -> hb16 bf16 hi/lo pair [n][16384]
__global__ __launch_bounds__(256) void lin2fin(
    const float* __restrict__ acc, const void* __restrict__ b2, const u32* __restrict__ meta,
    u16* __restrict__ hb16h, u16* __restrict__ hb16l)
{
    const int flag = meta[0];
    const int fo = threadIdx.x;
    const int m2 = blockIdx.x * 4 + threadIdx.y;
    const int n  = blockIdx.y;
    const size_t b = ((size_t)n * 1024 + (size_t)m2 * 4) * 64 + fo;
    float v = fmaxf(fmaxf(acc[b], acc[b + 64]), fmaxf(acc[b + 128], acc[b + 192]));
    v = fmaxf(v + ldw(b2, fo, flag), 0.f);
    const size_t oi = (size_t)n * 16384 + (size_t)m2 * 64 + fo;
    const u16 h = f2bf(v);
    hb16h[oi] = h;
    hb16l[oi] = f2bf(v - bf2f(h));
}

// ---------------------------------------------------------------------------
// FC1 via MFMA: (64 x 16384) @ (16384 x 512), split-K x32, no atomics.
// Grid (32 nt, 8 kg), 256 thr = 4 waves; wave kc = kg*4 + wave (K-chunk 512).
// A = hb16 hi/lo pair; B = Wh fp32, split to hi/lo in registers.
// part32[kc][m 64][h 512] fp32, each element written exactly once.
// ---------------------------------------------------------------------------
__global__ __launch_bounds__(256) void fc1_mfma(
    const u16* __restrict__ hb16h, const u16* __restrict__ hb16l,
    const void* __restrict__ Wh, const u32* __restrict__ meta,
    float* __restrict__ part32)
{
    const int flag = meta[0];
    const int tid  = threadIdx.x;
    const int wave = tid >> 6;
    const int lane = tid & 63;
    const int r16  = lane & 15;
    const int quad = lane >> 4;
    const int nt = blockIdx.x;                 // 0..31 -> h-tile of 16
    const int kc = blockIdx.y * 4 + wave;      // 0..31 -> K-chunk of 512

    v4f acc[4];
    #pragma unroll
    for (int mt = 0; mt < 4; ++mt) acc[mt] = (v4f){0.f, 0.f, 0.f, 0.f};

    const int h0 = nt * 16 + r16;
    for (int ks = 0; ks < 16; ++ks) {
        const int kb = kc * 512 + ks * 32 + quad * 8;
        // B-frag: Wh rows kb..kb+7, column h0 -> hi/lo pair in registers
        v8s bh, bl;
        #pragma unroll
        for (int j = 0; j < 8; ++j) {
            const float w = ldw(Wh, (size_t)(kb + j) * 512 + h0, flag);
            const u16 h = f2bf(w);
            bh[j] = (short)h;
            bl[j] = (short)f2bf(w - bf2f(h));
        }
        #pragma unroll
        for (int mt = 0; mt < 4; ++mt) {
            const size_t arow = (size_t)(mt * 16 + r16) * 16384 + kb;
            v8s ah = *(const v8s*)(hb16h + arow);
            v8s al = *(const v8s*)(hb16l + arow);
            acc[mt] = __builtin_amdgcn_mfma_f32_16x16x32_bf16(ah, bh, acc[mt], 0, 0, 0);
            acc[mt] = __builtin_amdgcn_mfma_f32_16x16x32_bf16(ah, bl, acc[mt], 0, 0, 0);
            acc[mt] = __builtin_amdgcn_mfma_f32_16x16x32_bf16(al, bh, acc[mt], 0, 0, 0);
        }
    }

    // D: col(lane&15) = h-local, row(quad*4+r) = batch m-local
    #pragma unroll
    for (int mt = 0; mt < 4; ++mt) {
        const int m = mt * 16 + quad * 4;
        float* p = part32 + (size_t)kc * 32768 + (size_t)m * 512 + h0;
        #pragma unroll
        for (int r = 0; r < 4; ++r) p[r * 512] = acc[mt][r];
    }
}

// FC1 combine (sum 32 partials) + bias + relu fused with FC2
__global__ void fc2_k(
    const float* __restrict__ part32, const void* __restrict__ bh,
    const void* __restrict__ Wo, const void* __restrict__ bo,
    const u32* __restrict__ meta, void* __restrict__ out)
{
    const int flag = meta[0];
    const int n = blockIdx.x;
    const int lane = threadIdx.x;   // 64 = 1 wave
    float p[10];
    #pragma unroll
    for (int o = 0; o < 10; ++o) p[o] = 0.f;
    for (int j = lane; j < 512; j += 64) {
        float s = 0.f;
        #pragma unroll 8
        for (int c = 0; c < 32; ++c) s += part32[(size_t)c * 32768 + (size_t)n * 512 + j];
        const float r = fmaxf(s + ldw(bh, j, flag), 0.f);
        #pragma unroll
        for (int o = 0; o < 10; ++o) p[o] += r * ldw(Wo, j * 10 + o, flag);
    }
    #pragma unroll
    for (int o = 0; o < 10; ++o) {
        for (int off = 32; off > 0; off >>= 1) p[o] += __shfl_down(p[o], off);
    }
    if (lane == 0) {
        #pragma unroll
        for (int o = 0; o < 10; ++o) {
            float v = p[o] + ldw(bo, o, flag);
            if (flag) ((u16*)out)[n * 10 + o] = f2bf(v);
            else      ((float*)out)[n * 10 + o] = v;
        }
    }
}

extern "C" void kernel_launch(void* const* d_in, const int* in_sizes, int n_in,
                              void* d_out, int out_size, void* d_ws, size_t ws_size,
                              hipStream_t stream)
{
    const void* x  = d_in[0];
    const void* L0 = d_in[1];
    const void* L1 = d_in[2];
    const void* W1 = d_in[3];
    const void* b1 = d_in[4];
    const void* W2 = d_in[5];
    const void* b2 = d_in[6];
    const void* Wh = d_in[7];
    const void* bh = d_in[8];
    const void* Wo = d_in[9];
    const void* bo = d_in[10];

    // ---- workspace carve-up (~135.1 MB; rounds 3-6 proved ws >= 135.1 MB) ----
    char* base = (char*)d_ws;
    size_t off = 0;
    u32*  meta = (u32*)(base + off);      off += 256;
    u16*  L0hi = (u16*)(base + off);      off += (size_t)33554432;
    u16*  L0lo = (u16*)(base + off);      off += (size_t)33554432;
    u16*  L1hi = (u16*)(base + off);      off += (size_t)2097152;
    u16*  L1lo = (u16*)(base + off);      off += (size_t)2097152;
    u16*  A1hi = (u16*)(base + off);      off += (size_t)25 * 524288;   // dead after lin1 -> Xt slots 1,2
    u16*  A1lo = (u16*)(base + off);      off += (size_t)3 * 524288;    // dead after layer-1 -> Xt slot 0
    off += (size_t)4194304 - 3 * 524288;  // Xt slot 0 pads to 4 MiB
    u16*  A2hi = (u16*)(base + off);      off += (size_t)3 * 4194304;
    u16*  A2lo = (u16*)(base + off);      off += (size_t)3 * 4194304;
    float* ACC2 = (float*)(base + off);   off += (size_t)16777216;
    u16*  hb16h = (u16*)(base + off);     off += (size_t)2097152;
    u16*  hb16l = (u16*)(base + off);     off += (size_t)2097152;
    float* unused_part = (float*)(base + off); off += (size_t)131072; (void)unused_part;
    u16*  W2th = (u16*)(base + off);      off += (size_t)102400;
    u16*  W2tl = (u16*)(base + off);      off += (size_t)102400;
    float* cpart  = ACC2;   // overlay: layer-1 split-K partials (8 MB) in ACC2
    float* part32 = ACC2;   // overlay: fc1 partials (4 MB) in ACC2 (ACC2 dead after lin2fin)
    u16* Xt[3] = { A1lo, A1hi, A1hi + 2097152 };

    // dtype detection + canonical hi/lo conversion + W2 transpose
    detect_k<<<1, 256, 0, stream>>>((const u32*)L0, meta);
    cvt_pair<<<2048, 256, 0, stream>>>(L0, L0hi, L0lo, meta, 16777216);
    cvt_pair<<<256, 256, 0, stream>>>(L1, L1hi, L1lo, meta, 1048576);
    cvt_pair<<<64, 256, 0, stream>>>(x, A1hi, A1lo, meta, 262144);  // slice 0
    w2t_k<<<200, 256, 0, stream>>>(W2, meta, W2th, W2tl);

    // ---- layer-1 Chebyshev recurrence: tiled split-K x8 + combine ----
    for (int k = 1; k < 25; ++k) {
        cheb_tile<0><<<dim3(64, 1, 8), 512, 0, stream>>>(
            L0hi, L0lo,
            A1hi + (size_t)(k - 1) * 262144, A1lo + (size_t)((k - 1) % 3) * 262144,
            (const u16*)0, (const u16*)0, (u16*)0, (u16*)0, cpart, (u16*)0,
            4096, 4096, 64, 512, 0.f, 0);
        const u16* pAh = (k >= 2) ? A1hi + (size_t)(k - 2) * 262144 : A1hi;
        const u16* pAl = A1lo + (size_t)(((k >= 2) ? (k - 2) : 0) % 3) * 262144;
        cheb_comb<<<1024, 256, 0, stream>>>(
            cpart, pAh, pAl,
            A1hi + (size_t)k * 262144, A1lo + (size_t)(k % 3) * 262144,
            262144, 8, (k == 1) ? 1.f : 2.f, (k >= 2) ? 1 : 0);
    }

    // linear1 + relu + pool4 -> layer-2 slice 0 (hi/lo) + transposed Xt0
    lin1_pool<<<dim3(16, 8, 64), dim3(64, 4), 0, stream>>>(
        A1hi, W1, b1, meta, A2hi, A2lo, Xt[0]);

    // ---- layer-2 recurrence (tiled, fused epilogue + Xt) + grouped MFMA lin2
    for (int k = 1; k < 25; ++k) {
        const u16* pBh = A2hi + (size_t)((k - 1) % 3) * 2097152;
        const u16* pBl = A2lo + (size_t)((k - 1) % 3) * 2097152;
        const u16* pAh = A2hi + (size_t)(((k >= 2) ? (k - 2) : 0) % 3) * 2097152;
        const u16* pAl = A2lo + (size_t)(((k >= 2) ? (k - 2) : 0) % 3) * 2097152;
        u16* pCh = A2hi + (size_t)(k % 3) * 2097152;
        u16* pCl = A2lo + (size_t)(k % 3) * 2097152;
        cheb_tile<1><<<dim3(16, 32, 1), 512, 0, stream>>>(
            L1hi, L1lo, pBh, pBl, pAh, pAl, pCh, pCl, (float*)0, Xt[k % 3],
            1024, 1024, 2048, 1024, (k == 1) ? 1.f : 2.f, (k >= 2) ? 1 : 0);
        if (k >= 2 && ((k - 2) % 3) == 0) {
            lin2_mfma<<<dim3(8, 64), 256, 0, stream>>>(
                Xt[0], Xt[1], Xt[2], W2th, W2tl, ACC2, k - 2, 3, (k == 2) ? 1 : 0);
        }
    }
    // final group: slice 24 (24 % 3 == 0 -> slot 0)
    lin2_mfma<<<dim3(8, 64), 256, 0, stream>>>(
        Xt[0], Xt[0], Xt[0], W2th, W2tl, ACC2, 24, 1, 0);

    // finish linear2: bias + relu + pool4 -> hb16 bf16 pair (ACC2 dead after)
    lin2fin<<<dim3(64, 64), dim3(64, 4), 0, stream>>>(ACC2, b2, meta, hb16h, hb16l);

    // FC head: MFMA fc1 (split-K partials, no atomics) + combine/fc2
    fc1_mfma<<<dim3(32, 8), 256, 0, stream>>>(hb16h, hb16l, Wh, meta, part32);
    fc2_k<<<64, 64, 0, stream>>>(part32, bh, Wo, bo, meta, d_out);
}

// Round 8
// 997.121 us; speedup vs baseline: 1.5286x; 1.4890x over previous
//
#include <hip/hip_runtime.h>

typedef unsigned short u16;
typedef unsigned int   u32;
typedef _Float16 f16;
typedef f16  v8h __attribute__((ext_vector_type(8)));
typedef f16  v4h __attribute__((ext_vector_type(4)));
typedef short v8s __attribute__((ext_vector_type(8)));
typedef float v4f __attribute__((ext_vector_type(4)));
typedef u16   v4u __attribute__((ext_vector_type(4)));

__device__ __forceinline__ float bf2f(u16 u) {
    union { float f; u32 i; } c; c.i = ((u32)u) << 16; return c.f;
}
__device__ __forceinline__ u16 f2bf(float f) {
    union { float f; u32 i; } c; c.f = f;
    u32 x = c.i;
    return (u16)((x + 0x7fffu + ((x >> 16) & 1u)) >> 16);
}
__device__ __forceinline__ float ldw(const void* p, long i, int flag) {
    return flag ? bf2f(((const u16*)p)[i]) : ((const float*)p)[i];
}

// ---------------------------------------------------------------------------
// dtype detector (round-3 validated: flag=0 on this harness -> fp32 inputs)
// ---------------------------------------------------------------------------
__global__ void detect_k(const u32* __restrict__ w, u32* __restrict__ meta) {
    __shared__ int cnt;
    if (threadIdx.x == 0) cnt = 0;
    __syncthreads();
    u32 v = w[(size_t)threadIdx.x * 4099];
    u32 f = (v >> 7) & 0xFFu;
    if (f >= 0x60u && f < 0x7Fu) atomicAdd(&cnt, 1);
    __syncthreads();
    if (threadIdx.x == 0) meta[0] = (cnt >= 192) ? 1u : 0u;
}

// Convert input (bf16 or fp32 per flag) -> fp16, 4 elems/thread.
__global__ void cvt_half(const void* __restrict__ in, f16* __restrict__ out,
                         const u32* __restrict__ meta, int n) {
    const int flag = meta[0];
    const int n4 = n >> 2;
    const int stride = gridDim.x * blockDim.x;
    for (int i = blockIdx.x * blockDim.x + threadIdx.x; i < n4; i += stride) {
        v4h o;
        if (flag) {
            v4u h = *(const v4u*)((const u16*)in + (size_t)i * 4);
            #pragma unroll
            for (int r = 0; r < 4; ++r) o[r] = (f16)bf2f(h[r]);
        } else {
            v4f v = *(const v4f*)((const float*)in + (size_t)i * 4);
            #pragma unroll
            for (int r = 0; r < 4; ++r) o[r] = (f16)v[r];
        }
        *(v4h*)(out + (size_t)i * 4) = o;
    }
}

// One-time W2 transpose: W2[f*25+kc][fo] -> W2t16[fo][kc*32+f] (fp16)
__global__ void w2t_k(const void* __restrict__ W2, const u32* __restrict__ meta,
                      f16* __restrict__ W2t16) {
    const int flag = meta[0];
    const int i = blockIdx.x * 256 + threadIdx.x;
    if (i >= 51200) return;
    const int k = i >> 6, fo = i & 63;
    const float w = ldw(W2, (size_t)k * 64 + fo, flag);
    const int f = k / 25, kc = k % 25;
    W2t16[(size_t)fo * 800 + kc * 32 + f] = (f16)w;
}

// ---------------------------------------------------------------------------
// Tiled Cheb GEMM (fp16 single-product): C = alpha*L@B - A
// Block: 64x64 tile, 256 thr = 4 waves (2x2), wave 32x32 via 2x2 MFMA
// 16x16x32 f16. LDS: 2 comps [64][72] f16 = 18 KB.
// FUSED=1: recurrence epilogue + Xt write (layer 2). FUSED=0: fp32 split-K
// partials (layer 1).
// ---------------------------------------------------------------------------
template<int FUSED>
__global__ __launch_bounds__(256) void cheb_tile(
    const f16* __restrict__ L, const f16* __restrict__ B, const f16* __restrict__ A,
    f16* __restrict__ C, float* __restrict__ Cpart, f16* __restrict__ Xt,
    int M, int V, int NC, int kc, float alpha, int useA)
{
    __shared__ f16 smem[2 * 64 * 72];            // A | B, rows padded to 72
    const int tid  = threadIdx.x;
    const int wave = tid >> 6;
    const int lane = tid & 63;
    const int r16  = lane & 15;
    const int quad = lane >> 4;
    const int wm = wave & 1, wn = wave >> 1;

    const int m0 = blockIdx.x * 64;
    const int n0 = blockIdx.y * 64;
    const int k0 = blockIdx.z * kc;

    const int sr = lane >> 3;                    // 0..7
    const int sc = lane & 7;                     // 0..7
    const int rloc = wave * 16 + sr;             // row, j=0 (+8 rows for j=1)
    const int lw  = rloc * 72 + sc * 8;

    v4f acc[2][2];
    #pragma unroll
    for (int i = 0; i < 2; ++i)
        #pragma unroll
        for (int j = 0; j < 2; ++j) acc[i][j] = (v4f){0.f, 0.f, 0.f, 0.f};

    const int arow0 = (wm * 32 + r16) * 72;
    const int arow1 = arow0 + 16 * 72;
    const int brow0 = 4608 + (wn * 32 + r16) * 72;
    const int brow1 = brow0 + 16 * 72;

    const int stages = kc >> 6;
    for (int st = 0; st < stages; ++st) {
        const int kk = k0 + st * 64;
        const size_t gA = (size_t)(m0 + rloc) * V + kk + sc * 8;
        const size_t gB = (size_t)(n0 + rloc) * V + kk + sc * 8;
        const size_t j8 = (size_t)8 * V;

        v8h t0 = *(const v8h*)(L + gA);
        v8h t1 = *(const v8h*)(L + gA + j8);
        v8h t2 = *(const v8h*)(B + gB);
        v8h t3 = *(const v8h*)(B + gB + j8);

        __syncthreads();                          // prev compute done before overwrite
        *(v8h*)(smem +        lw)       = t0;
        *(v8h*)(smem +        lw + 576) = t1;
        *(v8h*)(smem + 4608 + lw)       = t2;
        *(v8h*)(smem + 4608 + lw + 576) = t3;
        __syncthreads();

        #pragma unroll
        for (int s = 0; s < 2; ++s) {
            const int qo = (s * 4 + quad) * 8;
            v8h a0 = *(const v8h*)(smem + arow0 + qo);
            v8h a1 = *(const v8h*)(smem + arow1 + qo);
            v8h b0 = *(const v8h*)(smem + brow0 + qo);
            v8h b1 = *(const v8h*)(smem + brow1 + qo);
            acc[0][0] = __builtin_amdgcn_mfma_f32_16x16x32_f16(a0, b0, acc[0][0], 0, 0, 0);
            acc[0][1] = __builtin_amdgcn_mfma_f32_16x16x32_f16(a0, b1, acc[0][1], 0, 0, 0);
            acc[1][0] = __builtin_amdgcn_mfma_f32_16x16x32_f16(a1, b0, acc[1][0], 0, 0, 0);
            acc[1][1] = __builtin_amdgcn_mfma_f32_16x16x32_f16(a1, b1, acc[1][1], 0, 0, 0);
        }
    }

    #pragma unroll
    for (int j = 0; j < 2; ++j) {
        const int n = n0 + wn * 32 + j * 16 + r16;
        #pragma unroll
        for (int i = 0; i < 2; ++i) {
            const int mrow = m0 + wm * 32 + i * 16 + quad * 4;
            if (FUSED) {
                const size_t obase = (size_t)n * M + mrow;
                float vals[4];
                if (useA) {
                    v4h a4 = *(const v4h*)(A + obase);
                    #pragma unroll
                    for (int r = 0; r < 4; ++r)
                        vals[r] = alpha * acc[i][j][r] - (float)a4[r];
                } else {
                    #pragma unroll
                    for (int r = 0; r < 4; ++r) vals[r] = alpha * acc[i][j][r];
                }
                v4h co;
                #pragma unroll
                for (int r = 0; r < 4; ++r) co[r] = (f16)vals[r];
                *(v4h*)(C + obase) = co;
                // transposed copy for lin2 MFMA: Xt[(nb*1024 + u)*32 + f]
                const int nb = n >> 5, f = n & 31;
                f16* xt = Xt + ((size_t)(nb * 1024) + mrow) * 32 + f;
                #pragma unroll
                for (int r = 0; r < 4; ++r) xt[r * 32] = co[r];
            } else {
                float* cp = Cpart + ((size_t)(blockIdx.z * NC + n)) * M + mrow;
                *(v4f*)cp = acc[i][j];
            }
        }
    }
}

// Combine split-K partials + recurrence epilogue (layer 1, fp16 state).
__global__ __launch_bounds__(256) void cheb_comb(
    const float* __restrict__ Cpart, const f16* __restrict__ Aprev,
    f16* __restrict__ C, int total, int nkc, float alpha, int useA)
{
    const int idx = blockIdx.x * 256 + threadIdx.x;
    if (idx >= total) return;
    float s = 0.f;
    for (int c = 0; c < nkc; ++c) s += Cpart[(size_t)c * total + idx];
    float v = alpha * s;
    if (useA) v -= (float)Aprev[idx];
    C[idx] = (f16)v;
}

// ---------------------------------------------------------------------------
// Linear1 (25->32) + bias + relu + maxpool4 -> layer-2 slice0 (fp16) + Xt0.
// Each thread: 8 input m (16-B loads) -> 2 pooled outputs.
// ---------------------------------------------------------------------------
__global__ __launch_bounds__(256) void lin1_pool(
    const f16* __restrict__ S, const void* __restrict__ W1, const void* __restrict__ b1,
    const u32* __restrict__ meta, f16* __restrict__ O, f16* __restrict__ Xt0)
{
    const int flag = meta[0];
    const int g  = blockIdx.x * 64 + threadIdx.x;   // 0..511
    const int f  = blockIdx.y * 4 + threadIdx.y;    // 0..31
    const int n  = blockIdx.z;                      // 0..63
    float a[8];
    #pragma unroll
    for (int r = 0; r < 8; ++r) a[r] = 0.f;
    const size_t base = (size_t)n * 4096 + (size_t)g * 8;
    #pragma unroll
    for (int k = 0; k < 25; ++k) {
        v8h x8 = *(const v8h*)(S + (size_t)k * 262144 + base);
        float w = ldw(W1, k * 32 + f, flag);
        #pragma unroll
        for (int r = 0; r < 8; ++r) a[r] += (float)x8[r] * w;
    }
    const float b = ldw(b1, f, flag);
    float v0 = fmaxf(fmaxf(fmaxf(a[0], a[1]), fmaxf(a[2], a[3])) + b, 0.f);
    float v1 = fmaxf(fmaxf(fmaxf(a[4], a[5]), fmaxf(a[6], a[7])) + b, 0.f);
    const int m1 = g * 2;
    const size_t oi = ((size_t)n * 32 + f) * 1024 + m1;
    O[oi]     = (f16)v0;
    O[oi + 1] = (f16)v1;
    f16* xt = Xt0 + ((size_t)n * 1024 + m1) * 32 + f;
    xt[0]  = (f16)v0;
    xt[32] = (f16)v1;
}

// ---------------------------------------------------------------------------
// MFMA linear-2 accumulation over a group of up to 3 slices (fp16 single).
// ---------------------------------------------------------------------------
__global__ __launch_bounds__(256) void lin2_mfma(
    const f16* __restrict__ Xt0, const f16* __restrict__ Xt1, const f16* __restrict__ Xt2,
    const f16* __restrict__ W2t16,
    float* __restrict__ acc, int k0, int cnt, int zi)
{
    const int tid  = threadIdx.x;
    const int wave = tid >> 6;
    const int lane = tid & 63;
    const int r16  = lane & 15;
    const int quad = lane >> 4;
    const int n  = blockIdx.y;
    const int u0 = blockIdx.x * 128 + wave * 32;

    v4f a[2][4];
    #pragma unroll
    for (int i = 0; i < 2; ++i)
        #pragma unroll
        for (int j = 0; j < 4; ++j) a[i][j] = (v4f){0.f, 0.f, 0.f, 0.f};

    const f16* Xs[3] = {Xt0, Xt1, Xt2};
    for (int c = 0; c < cnt; ++c) {
        const f16* X = Xs[c];
        v8h a0 = *(const v8h*)(X + ((size_t)n * 1024 + u0 + r16) * 32 + quad * 8);
        v8h a1 = *(const v8h*)(X + ((size_t)n * 1024 + u0 + 16 + r16) * 32 + quad * 8);
        const int kb = (k0 + c) * 32 + quad * 8;
        #pragma unroll
        for (int j = 0; j < 4; ++j) {
            v8h bh = *(const v8h*)(W2t16 + (size_t)(j * 16 + r16) * 800 + kb);
            a[0][j] = __builtin_amdgcn_mfma_f32_16x16x32_f16(a0, bh, a[0][j], 0, 0, 0);
            a[1][j] = __builtin_amdgcn_mfma_f32_16x16x32_f16(a1, bh, a[1][j], 0, 0, 0);
        }
    }

    #pragma unroll
    for (int i = 0; i < 2; ++i) {
        const int u = u0 + i * 16 + quad * 4;
        #pragma unroll
        for (int j = 0; j < 4; ++j) {
            const int fo = j * 16 + r16;
            float* p = acc + ((size_t)n * 1024 + u) * 64 + fo;
            if (zi) {
                #pragma unroll
                for (int r = 0; r < 4; ++r) p[r * 64] = a[i][j][r];
            } else {
                #pragma unroll
                for (int r = 0; r < 4; ++r) p[r * 64] += a[i][j][r];
            }
        }
    }
}

// Finish linear-2: bias + relu + maxpool4 -> hb16 bf16 hi/lo pair [n][16384]
__global__ __launch_bounds__(256) void lin2fin(
    const float* __restrict__ acc, const void* __restrict__ b2, const u32* __restrict__ meta,
    u16* __restrict__ hb16h, u16* __restrict__ hb16l)
{
    const int flag = meta[0];
    const int fo = threadIdx.x;
    const int m2 = blockIdx.x * 4 + threadIdx.y;
    const int n  = blockIdx.y;
    const size_t b = ((size_t)n * 1024 + (size_t)m2 * 4) * 64 + fo;
    float v = fmaxf(fmaxf(acc[b], acc[b + 64]), fmaxf(acc[b + 128], acc[b + 192]));
    v = fmaxf(v + ldw(b2, fo, flag), 0.f);
    const size_t oi = (size_t)n * 16384 + (size_t)m2 * 64 + fo;
    const u16 h = f2bf(v);
    hb16h[oi] = h;
    hb16l[oi] = f2bf(v - bf2f(h));
}

// ---------------------------------------------------------------------------
// FC1 via MFMA: (64 x 16384) @ (16384 x 512), split-K x32, no atomics.
// ---------------------------------------------------------------------------
__global__ __launch_bounds__(256) void fc1_mfma(
    const u16* __restrict__ hb16h, const u16* __restrict__ hb16l,
    const void* __restrict__ Wh, const u32* __restrict__ meta,
    float* __restrict__ part32)
{
    const int flag = meta[0];
    const int tid  = threadIdx.x;
    const int wave = tid >> 6;
    const int lane = tid & 63;
    const int r16  = lane & 15;
    const int quad = lane >> 4;
    const int nt = blockIdx.x;                 // 0..31 -> h-tile of 16
    const int kc = blockIdx.y * 4 + wave;      // 0..31 -> K-chunk of 512

    v4f acc[4];
    #pragma unroll
    for (int mt = 0; mt < 4; ++mt) acc[mt] = (v4f){0.f, 0.f, 0.f, 0.f};

    const int h0 = nt * 16 + r16;
    for (int ks = 0; ks < 16; ++ks) {
        const int kb = kc * 512 + ks * 32 + quad * 8;
        v8s bh, bl;
        #pragma unroll
        for (int j = 0; j < 8; ++j) {
            const float w = ldw(Wh, (size_t)(kb + j) * 512 + h0, flag);
            const u16 h = f2bf(w);
            bh[j] = (short)h;
            bl[j] = (short)f2bf(w - bf2f(h));
        }
        #pragma unroll
        for (int mt = 0; mt < 4; ++mt) {
            const size_t arow = (size_t)(mt * 16 + r16) * 16384 + kb;
            v8s ah = *(const v8s*)(hb16h + arow);
            v8s al = *(const v8s*)(hb16l + arow);
            acc[mt] = __builtin_amdgcn_mfma_f32_16x16x32_bf16(ah, bh, acc[mt], 0, 0, 0);
            acc[mt] = __builtin_amdgcn_mfma_f32_16x16x32_bf16(ah, bl, acc[mt], 0, 0, 0);
            acc[mt] = __builtin_amdgcn_mfma_f32_16x16x32_bf16(al, bh, acc[mt], 0, 0, 0);
        }
    }

    #pragma unroll
    for (int mt = 0; mt < 4; ++mt) {
        const int m = mt * 16 + quad * 4;
        float* p = part32 + (size_t)kc * 32768 + (size_t)m * 512 + h0;
        #pragma unroll
        for (int r = 0; r < 4; ++r) p[r * 512] = acc[mt][r];
    }
}

// FC1 combine (sum 32 partials) + bias + relu fused with FC2
__global__ void fc2_k(
    const float* __restrict__ part32, const void* __restrict__ bh,
    const void* __restrict__ Wo, const void* __restrict__ bo,
    const u32* __restrict__ meta, void* __restrict__ out)
{
    const int flag = meta[0];
    const int n = blockIdx.x;
    const int lane = threadIdx.x;   // 64 = 1 wave
    float p[10];
    #pragma unroll
    for (int o = 0; o < 10; ++o) p[o] = 0.f;
    for (int j = lane; j < 512; j += 64) {
        float s = 0.f;
        #pragma unroll 8
        for (int c = 0; c < 32; ++c) s += part32[(size_t)c * 32768 + (size_t)n * 512 + j];
        const float r = fmaxf(s + ldw(bh, j, flag), 0.f);
        #pragma unroll
        for (int o = 0; o < 10; ++o) p[o] += r * ldw(Wo, j * 10 + o, flag);
    }
    #pragma unroll
    for (int o = 0; o < 10; ++o) {
        for (int off = 32; off > 0; off >>= 1) p[o] += __shfl_down(p[o], off);
    }
    if (lane == 0) {
        #pragma unroll
        for (int o = 0; o < 10; ++o) {
            float v = p[o] + ldw(bo, o, flag);
            if (flag) ((u16*)out)[n * 10 + o] = f2bf(v);
            else      ((float*)out)[n * 10 + o] = v;
        }
    }
}

extern "C" void kernel_launch(void* const* d_in, const int* in_sizes, int n_in,
                              void* d_out, int out_size, void* d_ws, size_t ws_size,
                              hipStream_t stream)
{
    const void* x  = d_in[0];
    const void* L0 = d_in[1];
    const void* L1 = d_in[2];
    const void* W1 = d_in[3];
    const void* b1 = d_in[4];
    const void* W2 = d_in[5];
    const void* b2 = d_in[6];
    const void* Wh = d_in[7];
    const void* bh = d_in[8];
    const void* Wo = d_in[9];
    const void* bo = d_in[10];

    // ---- workspace carve-up (~108 MB; rounds 3-7 proved ws >= 135.1 MB) ----
    char* base = (char*)d_ws;
    size_t off = 0;
    u32* meta  = (u32*)(base + off);     off += 256;
    f16* L016  = (f16*)(base + off);     off += (size_t)16777216 * 2;
    f16* L116  = (f16*)(base + off);     off += (size_t)1048576 * 2;
    f16* A116  = (f16*)(base + off);     off += (size_t)25 * 262144 * 2;
    float* cpart = (float*)(base + off); off += (size_t)8 * 262144 * 4;
    f16* A216  = (f16*)(base + off);     off += (size_t)3 * 2097152 * 2;
    f16* Xt16  = (f16*)(base + off);     off += (size_t)3 * 2097152 * 2;
    float* ACC2 = (float*)(base + off);  off += (size_t)16777216;
    u16* hb16h = (u16*)(base + off);     off += (size_t)2097152;
    u16* hb16l = (u16*)(base + off);     off += (size_t)2097152;
    float* part32 = (float*)(base + off); off += (size_t)4194304;
    f16* W2t16 = (f16*)(base + off);     off += (size_t)102400;
    f16* Xt[3] = { Xt16, Xt16 + 2097152, Xt16 + 2 * 2097152 };

    // dtype detection + fp16 conversion + W2 transpose
    detect_k<<<1, 256, 0, stream>>>((const u32*)L0, meta);
    cvt_half<<<2048, 256, 0, stream>>>(L0, L016, meta, 16777216);
    cvt_half<<<256, 256, 0, stream>>>(L1, L116, meta, 1048576);
    cvt_half<<<64, 256, 0, stream>>>(x, A116, meta, 262144);   // slice 0
    w2t_k<<<200, 256, 0, stream>>>(W2, meta, W2t16);

    // ---- layer-1 Chebyshev recurrence: tiled split-K x8 + combine ----
    for (int k = 1; k < 25; ++k) {
        cheb_tile<0><<<dim3(64, 1, 8), 256, 0, stream>>>(
            L016, A116 + (size_t)(k - 1) * 262144, (const f16*)0,
            (f16*)0, cpart, (f16*)0,
            4096, 4096, 64, 512, 0.f, 0);
        const f16* pA = (k >= 2) ? A116 + (size_t)(k - 2) * 262144 : A116;
        cheb_comb<<<1024, 256, 0, stream>>>(
            cpart, pA, A116 + (size_t)k * 262144,
            262144, 8, (k == 1) ? 1.f : 2.f, (k >= 2) ? 1 : 0);
    }

    // linear1 + relu + pool4 -> layer-2 slice 0 (fp16) + transposed Xt0
    lin1_pool<<<dim3(8, 8, 64), dim3(64, 4), 0, stream>>>(
        A116, W1, b1, meta, A216, Xt[0]);

    // ---- layer-2 recurrence (tiled, fused epilogue + Xt) + grouped MFMA lin2
    for (int k = 1; k < 25; ++k) {
        const f16* pB = A216 + (size_t)((k - 1) % 3) * 2097152;
        const f16* pA = A216 + (size_t)(((k >= 2) ? (k - 2) : 0) % 3) * 2097152;
        f16* pC = A216 + (size_t)(k % 3) * 2097152;
        cheb_tile<1><<<dim3(16, 32, 1), 256, 0, stream>>>(
            L116, pB, pA, pC, (float*)0, Xt[k % 3],
            1024, 1024, 2048, 1024, (k == 1) ? 1.f : 2.f, (k >= 2) ? 1 : 0);
        if (k >= 2 && ((k - 2) % 3) == 0) {
            // slices k-2,k-1,k occupy Xt slots 0,1,2 (since (k-2)%3==0)
            lin2_mfma<<<dim3(8, 64), 256, 0, stream>>>(
                Xt[0], Xt[1], Xt[2], W2t16, ACC2, k - 2, 3, (k == 2) ? 1 : 0);
        }
    }
    // final group: slice 24 (24 % 3 == 0 -> slot 0)
    lin2_mfma<<<dim3(8, 64), 256, 0, stream>>>(
        Xt[0], Xt[0], Xt[0], W2t16, ACC2, 24, 1, 0);

    // finish linear2: bias + relu + pool4 -> hb16 bf16 pair
    lin2fin<<<dim3(64, 64), dim3(64, 4), 0, stream>>>(ACC2, b2, meta, hb16h, hb16l);

    // FC head: MFMA fc1 (split-K partials, no atomics) + combine/fc2
    fc1_mfma<<<dim3(32, 8), 256, 0, stream>>>(hb16h, hb16l, Wh, meta, part32);
    fc2_k<<<64, 64, 0, stream>>>(part32, bh, Wo, bo, meta, d_out);
}

// Round 10
// 991.678 us; speedup vs baseline: 1.5370x; 1.0055x over previous
//
#include <hip/hip_runtime.h>

typedef unsigned short u16;
typedef unsigned int   u32;
typedef _Float16 f16;
typedef f16  v8h __attribute__((ext_vector_type(8)));
typedef f16  v4h __attribute__((ext_vector_type(4)));
typedef short v8s __attribute__((ext_vector_type(8)));
typedef float v4f __attribute__((ext_vector_type(4)));
typedef u16   v4u __attribute__((ext_vector_type(4)));

__device__ __forceinline__ float bf2f(u16 u) {
    union { float f; u32 i; } c; c.i = ((u32)u) << 16; return c.f;
}
__device__ __forceinline__ u16 f2bf(float f) {
    union { float f; u32 i; } c; c.f = f;
    u32 x = c.i;
    return (u16)((x + 0x7fffu + ((x >> 16) & 1u)) >> 16);
}
__device__ __forceinline__ float ldw(const void* p, long i, int flag) {
    return flag ? bf2f(((const u16*)p)[i]) : ((const float*)p)[i];
}

// ---------------------------------------------------------------------------
// dtype detector (round-3 validated: flag=0 on this harness -> fp32 inputs)
// ---------------------------------------------------------------------------
__global__ void detect_k(const u32* __restrict__ w, u32* __restrict__ meta) {
    __shared__ int cnt;
    if (threadIdx.x == 0) cnt = 0;
    __syncthreads();
    u32 v = w[(size_t)threadIdx.x * 4099];
    u32 f = (v >> 7) & 0xFFu;
    if (f >= 0x60u && f < 0x7Fu) atomicAdd(&cnt, 1);
    __syncthreads();
    if (threadIdx.x == 0) meta[0] = (cnt >= 192) ? 1u : 0u;
}

// Convert input (bf16 or fp32 per flag) -> fp16, 4 elems/thread.
__global__ void cvt_half(const void* __restrict__ in, f16* __restrict__ out,
                         const u32* __restrict__ meta, int n) {
    const int flag = meta[0];
    const int n4 = n >> 2;
    const int stride = gridDim.x * blockDim.x;
    for (int i = blockIdx.x * blockDim.x + threadIdx.x; i < n4; i += stride) {
        v4h o;
        if (flag) {
            v4u h = *(const v4u*)((const u16*)in + (size_t)i * 4);
            #pragma unroll
            for (int r = 0; r < 4; ++r) o[r] = (f16)bf2f(h[r]);
        } else {
            v4f v = *(const v4f*)((const float*)in + (size_t)i * 4);
            #pragma unroll
            for (int r = 0; r < 4; ++r) o[r] = (f16)v[r];
        }
        *(v4h*)(out + (size_t)i * 4) = o;
    }
}

// One-time W2 transpose: W2[f*25+kc][fo] -> W2t16[fo][kc*32+f] (fp16)
__global__ void w2t_k(const void* __restrict__ W2, const u32* __restrict__ meta,
                      f16* __restrict__ W2t16) {
    const int flag = meta[0];
    const int i = blockIdx.x * 256 + threadIdx.x;
    if (i >= 51200) return;
    const int k = i >> 6, fo = i & 63;
    const float w = ldw(W2, (size_t)k * 64 + fo, flag);
    const int f = k / 25, kc = k % 25;
    W2t16[(size_t)fo * 800 + kc * 32 + f] = (f16)w;
}

// ---------------------------------------------------------------------------
// Tiled Cheb GEMM (fp16 single-product): C = alpha*L@B - A
// Block: 64x64 tile, 256 thr = 4 waves (2x2), wave 32x32 via 2x2 MFMA
// 16x16x32 f16. LDS: 2 comps [64][72] f16 = 18 KB.
// FUSED=1: recurrence epilogue + Xt write (layer 2). FUSED=0: fp32 split-K
// partials (layer 1).
// ---------------------------------------------------------------------------
template<int FUSED>
__global__ __launch_bounds__(256) void cheb_tile(
    const f16* __restrict__ L, const f16* __restrict__ B, const f16* __restrict__ A,
    f16* __restrict__ C, float* __restrict__ Cpart, f16* __restrict__ Xt,
    int M, int V, int NC, int kc, float alpha, int useA)
{
    __shared__ f16 smem[2 * 64 * 72];            // A | B, rows padded to 72
    const int tid  = threadIdx.x;
    const int wave = tid >> 6;
    const int lane = tid & 63;
    const int r16  = lane & 15;
    const int quad = lane >> 4;
    const int wm = wave & 1, wn = wave >> 1;

    const int m0 = blockIdx.x * 64;
    const int n0 = blockIdx.y * 64;
    const int k0 = blockIdx.z * kc;

    const int sr = lane >> 3;                    // 0..7
    const int sc = lane & 7;                     // 0..7
    const int rloc = wave * 16 + sr;             // row, j=0 (+8 rows for j=1)
    const int lw  = rloc * 72 + sc * 8;

    v4f acc[2][2];
    #pragma unroll
    for (int i = 0; i < 2; ++i)
        #pragma unroll
        for (int j = 0; j < 2; ++j) acc[i][j] = (v4f){0.f, 0.f, 0.f, 0.f};

    const int arow0 = (wm * 32 + r16) * 72;
    const int arow1 = arow0 + 16 * 72;
    const int brow0 = 4608 + (wn * 32 + r16) * 72;
    const int brow1 = brow0 + 16 * 72;

    const int stages = kc >> 6;
    for (int st = 0; st < stages; ++st) {
        const int kk = k0 + st * 64;
        const size_t gA = (size_t)(m0 + rloc) * V + kk + sc * 8;
        const size_t gB = (size_t)(n0 + rloc) * V + kk + sc * 8;
        const size_t j8 = (size_t)8 * V;

        v8h t0 = *(const v8h*)(L + gA);
        v8h t1 = *(const v8h*)(L + gA + j8);
        v8h t2 = *(const v8h*)(B + gB);
        v8h t3 = *(const v8h*)(B + gB + j8);

        __syncthreads();                          // prev compute done before overwrite
        *(v8h*)(smem +        lw)       = t0;
        *(v8h*)(smem +        lw + 576) = t1;
        *(v8h*)(smem + 4608 + lw)       = t2;
        *(v8h*)(smem + 4608 + lw + 576) = t3;
        __syncthreads();

        #pragma unroll
        for (int s = 0; s < 2; ++s) {
            const int qo = (s * 4 + quad) * 8;
            v8h a0 = *(const v8h*)(smem + arow0 + qo);
            v8h a1 = *(const v8h*)(smem + arow1 + qo);
            v8h b0 = *(const v8h*)(smem + brow0 + qo);
            v8h b1 = *(const v8h*)(smem + brow1 + qo);
            acc[0][0] = __builtin_amdgcn_mfma_f32_16x16x32_f16(a0, b0, acc[0][0], 0, 0, 0);
            acc[0][1] = __builtin_amdgcn_mfma_f32_16x16x32_f16(a0, b1, acc[0][1], 0, 0, 0);
            acc[1][0] = __builtin_amdgcn_mfma_f32_16x16x32_f16(a1, b0, acc[1][0], 0, 0, 0);
            acc[1][1] = __builtin_amdgcn_mfma_f32_16x16x32_f16(a1, b1, acc[1][1], 0, 0, 0);
        }
    }

    #pragma unroll
    for (int j = 0; j < 2; ++j) {
        const int n = n0 + wn * 32 + j * 16 + r16;
        #pragma unroll
        for (int i = 0; i < 2; ++i) {
            const int mrow = m0 + wm * 32 + i * 16 + quad * 4;
            if (FUSED) {
                const size_t obase = (size_t)n * M + mrow;
                float vals[4];
                if (useA) {
                    v4h a4 = *(const v4h*)(A + obase);
                    #pragma unroll
                    for (int r = 0; r < 4; ++r)
                        vals[r] = alpha * acc[i][j][r] - (float)a4[r];
                } else {
                    #pragma unroll
                    for (int r = 0; r < 4; ++r) vals[r] = alpha * acc[i][j][r];
                }
                v4h co;
                #pragma unroll
                for (int r = 0; r < 4; ++r) co[r] = (f16)vals[r];
                *(v4h*)(C + obase) = co;
                // transposed copy for lin2 MFMA: Xt[(nb*1024 + u)*32 + f]
                const int nb = n >> 5, f = n & 31;
                f16* xt = Xt + ((size_t)(nb * 1024) + mrow) * 32 + f;
                #pragma unroll
                for (int r = 0; r < 4; ++r) xt[r * 32] = co[r];
            } else {
                float* cp = Cpart + ((size_t)(blockIdx.z * NC + n)) * M + mrow;
                *(v4f*)cp = acc[i][j];
            }
        }
    }
}

// Combine split-K partials + recurrence epilogue (layer 1, fp16 state).
__global__ __launch_bounds__(256) void cheb_comb(
    const float* __restrict__ Cpart, const f16* __restrict__ Aprev,
    f16* __restrict__ C, int total, int nkc, float alpha, int useA)
{
    const int idx = blockIdx.x * 256 + threadIdx.x;
    if (idx >= total) return;
    float s = 0.f;
    for (int c = 0; c < nkc; ++c) s += Cpart[(size_t)c * total + idx];
    float v = alpha * s;
    if (useA) v -= (float)Aprev[idx];
    C[idx] = (f16)v;
}

// ---------------------------------------------------------------------------
// Linear1 (25->32) + bias + relu + maxpool4 -> layer-2 slice0 (fp16) + Xt0.
// Each thread: 8 input m (16-B loads) -> 2 pooled outputs.
// ---------------------------------------------------------------------------
__global__ __launch_bounds__(256) void lin1_pool(
    const f16* __restrict__ S, const void* __restrict__ W1, const void* __restrict__ b1,
    const u32* __restrict__ meta, f16* __restrict__ O, f16* __restrict__ Xt0)
{
    const int flag = meta[0];
    const int g  = blockIdx.x * 64 + threadIdx.x;   // 0..511
    const int f  = blockIdx.y * 4 + threadIdx.y;    // 0..31
    const int n  = blockIdx.z;                      // 0..63
    float a[8];
    #pragma unroll
    for (int r = 0; r < 8; ++r) a[r] = 0.f;
    const size_t base = (size_t)n * 4096 + (size_t)g * 8;
    #pragma unroll
    for (int k = 0; k < 25; ++k) {
        v8h x8 = *(const v8h*)(S + (size_t)k * 262144 + base);
        float w = ldw(W1, k * 32 + f, flag);
        #pragma unroll
        for (int r = 0; r < 8; ++r) a[r] += (float)x8[r] * w;
    }
    const float b = ldw(b1, f, flag);
    float v0 = fmaxf(fmaxf(fmaxf(a[0], a[1]), fmaxf(a[2], a[3])) + b, 0.f);
    float v1 = fmaxf(fmaxf(fmaxf(a[4], a[5]), fmaxf(a[6], a[7])) + b, 0.f);
    const int m1 = g * 2;
    const size_t oi = ((size_t)n * 32 + f) * 1024 + m1;
    O[oi]     = (f16)v0;
    O[oi + 1] = (f16)v1;
    f16* xt = Xt0 + ((size_t)n * 1024 + m1) * 32 + f;
    xt[0]  = (f16)v0;
    xt[32] = (f16)v1;
}

// ---------------------------------------------------------------------------
// MFMA linear-2 accumulation over a group of up to 3 slices (fp16 single).
// ---------------------------------------------------------------------------
__global__ __launch_bounds__(256) void lin2_mfma(
    const f16* __restrict__ Xt0, const f16* __restrict__ Xt1, const f16* __restrict__ Xt2,
    const f16* __restrict__ W2t16,
    float* __restrict__ acc, int k0, int cnt, int zi)
{
    const int tid  = threadIdx.x;
    const int wave = tid >> 6;
    const int lane = tid & 63;
    const int r16  = lane & 15;
    const int quad = lane >> 4;
    const int n  = blockIdx.y;
    const int u0 = blockIdx.x * 128 + wave * 32;

    v4f a[2][4];
    #pragma unroll
    for (int i = 0; i < 2; ++i)
        #pragma unroll
        for (int j = 0; j < 4; ++j) a[i][j] = (v4f){0.f, 0.f, 0.f, 0.f};

    const f16* Xs[3] = {Xt0, Xt1, Xt2};
    for (int c = 0; c < cnt; ++c) {
        const f16* X = Xs[c];
        v8h a0 = *(const v8h*)(X + ((size_t)n * 1024 + u0 + r16) * 32 + quad * 8);
        v8h a1 = *(const v8h*)(X + ((size_t)n * 1024 + u0 + 16 + r16) * 32 + quad * 8);
        const int kb = (k0 + c) * 32 + quad * 8;
        #pragma unroll
        for (int j = 0; j < 4; ++j) {
            v8h bh = *(const v8h*)(W2t16 + (size_t)(j * 16 + r16) * 800 + kb);
            a[0][j] = __builtin_amdgcn_mfma_f32_16x16x32_f16(a0, bh, a[0][j], 0, 0, 0);
            a[1][j] = __builtin_amdgcn_mfma_f32_16x16x32_f16(a1, bh, a[1][j], 0, 0, 0);
        }
    }

    #pragma unroll
    for (int i = 0; i < 2; ++i) {
        const int u = u0 + i * 16 + quad * 4;
        #pragma unroll
        for (int j = 0; j < 4; ++j) {
            const int fo = j * 16 + r16;
            float* p = acc + ((size_t)n * 1024 + u) * 64 + fo;
            if (zi) {
                #pragma unroll
                for (int r = 0; r < 4; ++r) p[r * 64] = a[i][j][r];
            } else {
                #pragma unroll
                for (int r = 0; r < 4; ++r) p[r * 64] += a[i][j][r];
            }
        }
    }
}

// Finish linear-2: bias + relu + maxpool4 -> hb16 bf16 hi/lo pair [n][16384]
__global__ __launch_bounds__(256) void lin2fin(
    const float* __restrict__ acc, const void* __restrict__ b2, const u32* __restrict__ meta,
    u16* __restrict__ hb16h, u16* __restrict__ hb16l)
{
    const int flag = meta[0];
    const int fo = threadIdx.x;
    const int m2 = blockIdx.x * 4 + threadIdx.y;
    const int n  = blockIdx.y;
    const size_t b = ((size_t)n * 1024 + (size_t)m2 * 4) * 64 + fo;
    float v = fmaxf(fmaxf(acc[b], acc[b + 64]), fmaxf(acc[b + 128], acc[b + 192]));
    v = fmaxf(v + ldw(b2, fo, flag), 0.f);
    const size_t oi = (size_t)n * 16384 + (size_t)m2 * 64 + fo;
    const u16 h = f2bf(v);
    hb16h[oi] = h;
    hb16l[oi] = f2bf(v - bf2f(h));
}

// ---------------------------------------------------------------------------
// FC1 via MFMA: (64 x 16384) @ (16384 x 512), split-K x128, no atomics.
// Grid (32 nt, 32 kg), 4 waves; wave kc = kg*4+wave (K-chunk 128).
// ---------------------------------------------------------------------------
__global__ __launch_bounds__(256) void fc1_mfma(
    const u16* __restrict__ hb16h, const u16* __restrict__ hb16l,
    const void* __restrict__ Wh, const u32* __restrict__ meta,
    float* __restrict__ part128)
{
    const int flag = meta[0];
    const int tid  = threadIdx.x;
    const int wave = tid >> 6;
    const int lane = tid & 63;
    const int r16  = lane & 15;
    const int quad = lane >> 4;
    const int nt = blockIdx.x;                 // 0..31 -> h-tile of 16
    const int kc = blockIdx.y * 4 + wave;      // 0..127 -> K-chunk of 128

    v4f acc[4];
    #pragma unroll
    for (int mt = 0; mt < 4; ++mt) acc[mt] = (v4f){0.f, 0.f, 0.f, 0.f};

    const int h0 = nt * 16 + r16;
    for (int ks = 0; ks < 4; ++ks) {
        const int kb = kc * 128 + ks * 32 + quad * 8;
        v8s bh, bl;
        #pragma unroll
        for (int j = 0; j < 8; ++j) {
            const float w = ldw(Wh, (size_t)(kb + j) * 512 + h0, flag);
            const u16 h = f2bf(w);
            bh[j] = (short)h;
            bl[j] = (short)f2bf(w - bf2f(h));
        }
        #pragma unroll
        for (int mt = 0; mt < 4; ++mt) {
            const size_t arow = (size_t)(mt * 16 + r16) * 16384 + kb;
            v8s ah = *(const v8s*)(hb16h + arow);
            v8s al = *(const v8s*)(hb16l + arow);
            acc[mt] = __builtin_amdgcn_mfma_f32_16x16x32_bf16(ah, bh, acc[mt], 0, 0, 0);
            acc[mt] = __builtin_amdgcn_mfma_f32_16x16x32_bf16(ah, bl, acc[mt], 0, 0, 0);
            acc[mt] = __builtin_amdgcn_mfma_f32_16x16x32_bf16(al, bh, acc[mt], 0, 0, 0);
        }
    }

    #pragma unroll
    for (int mt = 0; mt < 4; ++mt) {
        const int m = mt * 16 + quad * 4;
        float* p = part128 + (size_t)kc * 32768 + (size_t)m * 512 + h0;
        #pragma unroll
        for (int r = 0; r < 4; ++r) p[r * 512] = acc[mt][r];
    }
}

// Combine fc1 split-K partials: partC[idx] = sum_c part128[c][idx]
__global__ __launch_bounds__(256) void fc1comb(
    const float* __restrict__ part128, float* __restrict__ partC)
{
    const int idx = blockIdx.x * 256 + threadIdx.x;   // 0..32767
    float s = 0.f;
    #pragma unroll 8
    for (int c = 0; c < 128; ++c) s += part128[(size_t)c * 32768 + idx];
    partC[idx] = s;
}

// FC1 bias + relu fused with FC2
__global__ void fc2_k(
    const float* __restrict__ partC, const void* __restrict__ bh,
    const void* __restrict__ Wo, const void* __restrict__ bo,
    const u32* __restrict__ meta, void* __restrict__ out)
{
    const int flag = meta[0];
    const int n = blockIdx.x;
    const int lane = threadIdx.x;   // 64 = 1 wave
    float p[10];
    #pragma unroll
    for (int o = 0; o < 10; ++o) p[o] = 0.f;
    for (int j = lane; j < 512; j += 64) {
        const float r = fmaxf(partC[(size_t)n * 512 + j] + ldw(bh, j, flag), 0.f);
        #pragma unroll
        for (int o = 0; o < 10; ++o) p[o] += r * ldw(Wo, j * 10 + o, flag);
    }
    #pragma unroll
    for (int o = 0; o < 10; ++o) {
        for (int off = 32; off > 0; off >>= 1) p[o] += __shfl_down(p[o], off);
    }
    if (lane == 0) {
        #pragma unroll
        for (int o = 0; o < 10; ++o) {
            float v = p[o] + ldw(bo, o, flag);
            if (flag) ((u16*)out)[n * 10 + o] = f2bf(v);
            else      ((float*)out)[n * 10 + o] = v;
        }
    }
}

extern "C" void kernel_launch(void* const* d_in, const int* in_sizes, int n_in,
                              void* d_out, int out_size, void* d_ws, size_t ws_size,
                              hipStream_t stream)
{
    const void* x  = d_in[0];
    const void* L0 = d_in[1];
    const void* L1 = d_in[2];
    const void* W1 = d_in[3];
    const void* b1 = d_in[4];
    const void* W2 = d_in[5];
    const void* b2 = d_in[6];
    const void* Wh = d_in[7];
    const void* bh = d_in[8];
    const void* Wo = d_in[9];
    const void* bo = d_in[10];

    // ---- workspace carve-up (~104 MB) ----
    char* base = (char*)d_ws;
    size_t off = 0;
    u32* meta  = (u32*)(base + off);     off += 256;
    f16* L016  = (f16*)(base + off);     off += (size_t)16777216 * 2;
    f16* L116  = (f16*)(base + off);     off += (size_t)1048576 * 2;
    f16* A116  = (f16*)(base + off);     off += (size_t)25 * 262144 * 2;
    float* cpart = (float*)(base + off); off += (size_t)8 * 262144 * 4;
    f16* A216  = (f16*)(base + off);     off += (size_t)3 * 2097152 * 2;
    f16* Xt16  = (f16*)(base + off);     off += (size_t)3 * 2097152 * 2;
    float* ACC2 = (float*)(base + off);  off += (size_t)16777216;
    u16* hb16h = (u16*)(base + off);     off += (size_t)2097152;
    u16* hb16l = (u16*)(base + off);     off += (size_t)2097152;
    float* partC = (float*)(base + off); off += (size_t)131072;
    f16* W2t16 = (f16*)(base + off);     off += (size_t)102400;
    f16* Xt[3] = { Xt16, Xt16 + 2097152, Xt16 + 2 * 2097152 };
    float* part128 = ACC2;   // overlay: fc1 partials (16.78 MB) — ACC2 dead after lin2fin

    // dtype detection + fp16 conversion + W2 transpose
    detect_k<<<1, 256, 0, stream>>>((const u32*)L0, meta);
    cvt_half<<<2048, 256, 0, stream>>>(L0, L016, meta, 16777216);
    cvt_half<<<256, 256, 0, stream>>>(L1, L116, meta, 1048576);
    cvt_half<<<64, 256, 0, stream>>>(x, A116, meta, 262144);   // slice 0
    w2t_k<<<200, 256, 0, stream>>>(W2, meta, W2t16);

    // ---- layer-1 Chebyshev recurrence: tiled split-K x8 + combine ----
    for (int k = 1; k < 25; ++k) {
        cheb_tile<0><<<dim3(64, 1, 8), 256, 0, stream>>>(
            L016, A116 + (size_t)(k - 1) * 262144, (const f16*)0,
            (f16*)0, cpart, (f16*)0,
            4096, 4096, 64, 512, 0.f, 0);
        const f16* pA = (k >= 2) ? A116 + (size_t)(k - 2) * 262144 : A116;
        cheb_comb<<<1024, 256, 0, stream>>>(
            cpart, pA, A116 + (size_t)k * 262144,
            262144, 8, (k == 1) ? 1.f : 2.f, (k >= 2) ? 1 : 0);
    }

    // linear1 + relu + pool4 -> layer-2 slice 0 (fp16) + transposed Xt0
    lin1_pool<<<dim3(8, 8, 64), dim3(64, 4), 0, stream>>>(
        A116, W1, b1, meta, A216, Xt[0]);

    // ---- layer-2 recurrence (tiled, fused epilogue + Xt) + grouped MFMA lin2
    for (int k = 1; k < 25; ++k) {
        const f16* pB = A216 + (size_t)((k - 1) % 3) * 2097152;
        const f16* pA = A216 + (size_t)(((k >= 2) ? (k - 2) : 0) % 3) * 2097152;
        f16* pC = A216 + (size_t)(k % 3) * 2097152;
        cheb_tile<1><<<dim3(16, 32, 1), 256, 0, stream>>>(
            L116, pB, pA, pC, (float*)0, Xt[k % 3],
            1024, 1024, 2048, 1024, (k == 1) ? 1.f : 2.f, (k >= 2) ? 1 : 0);
        if (k >= 2 && ((k - 2) % 3) == 0) {
            // slices k-2,k-1,k occupy Xt slots 0,1,2 (since (k-2)%3==0)
            lin2_mfma<<<dim3(8, 64), 256, 0, stream>>>(
                Xt[0], Xt[1], Xt[2], W2t16, ACC2, k - 2, 3, (k == 2) ? 1 : 0);
        }
    }
    // final group: slice 24 (24 % 3 == 0 -> slot 0)
    lin2_mfma<<<dim3(8, 64), 256, 0, stream>>>(
        Xt[0], Xt[0], Xt[0], W2t16, ACC2, 24, 1, 0);

    // finish linear2: bias + relu + pool4 -> hb16 bf16 pair (ACC2 dead after)
    lin2fin<<<dim3(64, 64), dim3(64, 4), 0, stream>>>(ACC2, b2, meta, hb16h, hb16l);

    // FC head: MFMA fc1 (split-K x128, no atomics) + combine + fc2
    fc1_mfma<<<dim3(32, 32), 256, 0, stream>>>(hb16h, hb16l, Wh, meta, part128);
    fc1comb<<<128, 256, 0, stream>>>(part128, partC);
    fc2_k<<<64, 64, 0, stream>>>(partC, bh, Wo, bo, meta, d_out);
}